// Round 4
// baseline (4319.904 us; speedup 1.0000x reference)
//
#include <hip/hip_runtime.h>
#include <stdint.h>
#include <math.h>

namespace {

constexpr int kH = 160, kW = 160, kN = 8;
constexpr int kHW = kH * kW;              // 25600
constexpr int kM = kHW * 9;               // 230400 anchors / image
constexpr int kPre = 6000;
constexpr int kPost = 1000;
constexpr int kCand = 6016;
constexpr int kWords = 94;                // ceil(6016/64)
constexpr double kClampD = 4.135166556742356;  // np.log(1000/16) in f64

// ---- workspace layout (bytes) ----
constexpr size_t OFF_SCORES = 0;
constexpr size_t SZ_SCORES  = (size_t)kN * kM * 8;                 // 14.75 MB (f64)
constexpr size_t OFF_SIDX   = OFF_SCORES + SZ_SCORES;
constexpr size_t SZ_SIDX    = (size_t)kN * kPre * 4;
constexpr size_t OFF_EQ     = OFF_SIDX + SZ_SIDX;
constexpr size_t SZ_EQ      = (size_t)kN * 8192 * 4;
constexpr size_t OFF_CAND   = OFF_EQ + SZ_EQ;
constexpr size_t SZ_CAND    = (size_t)kN * 6 * kCand * 8;          // f64
constexpr size_t OFF_MASK   = OFF_CAND + SZ_CAND;
constexpr size_t SZ_MASK    = (size_t)kN * kWords * kCand * 8;     // 36.2 MB
constexpr size_t WS_NEED    = OFF_MASK + SZ_MASK;                  // ~53.7 MB

// base-anchor half extents (f32 of the f64 values, a = 3*size_idx + ratio_idx)
__constant__ float c_hw[9] = {
  22.627416997969522f, 16.0f, 11.313708498984761f,
  45.254833995939045f, 32.0f, 22.627416997969522f,
  90.509667991878090f, 64.0f, 45.254833995939045f};
__constant__ float c_hh[9] = {
  11.313708498984761f, 16.0f, 22.627416997969522f,
  22.627416997969522f, 32.0f, 45.254833995939045f,
  45.254833995939045f, 64.0f, 90.509667991878090f};

__device__ __forceinline__ uint64_t ordd(double d) {
  uint64_t u = (uint64_t)__double_as_longlong(d);
  return (u >> 63) ? ~u : (u | 0x8000000000000000ull);
}
__device__ __forceinline__ float4 ld4(const float* p) {
  return *reinterpret_cast<const float4*>(p);
}

// ================= fused conv3x3(f64 acc) + relu + cls head ===========
// grid (3 px-tiles of 64, 160 h, 8 n), 256 threads = 16 px-groups x 16 oc-groups.
// All accumulation in f64 (association-independent at the 1e-15 level).
struct SA { float in_s[8][3][72]; float w_s[8][9][132]; };   // 6.9K + 38K
struct SB { double x_s[128][64]; float w9[9][128]; };        // 64K + 4.6K
union SU { SA a; SB b; };

__global__ __launch_bounds__(256) void conv_cls_kernel(
    const float* __restrict__ feat, const float* __restrict__ w1,
    const float* __restrict__ b1, const float* __restrict__ cw,
    const float* __restrict__ cb,
    double* __restrict__ scores)
{
  __shared__ __align__(16) SU sm;
  const int bx = blockIdx.x, h = blockIdx.y, n = blockIdx.z;
  const int px0 = bx * 64;
  const int t = threadIdx.x;
  const int pg = t & 15, og = t >> 4;
  const float* fbase = feat + (size_t)n * 128 * kHW;

  double acc[8][4];
  #pragma unroll
  for (int oi = 0; oi < 8; ++oi)
    #pragma unroll
    for (int pi = 0; pi < 4; ++pi) acc[oi][pi] = 0.0;

  for (int ic0 = 0; ic0 < 128; ic0 += 8) {
    // stage input: 8 ic x 3 rows x 66 cols (col c -> w = px0-1+c), zero-pad OOB
    for (int idx = t; idx < 8 * 3 * 66; idx += 256) {
      int c = idx % 66, rr = (idx / 66) % 3, ic = idx / 198;
      int wcol = px0 - 1 + c, hh = h - 1 + rr;
      float v = 0.f;
      if ((unsigned)wcol < (unsigned)kW && (unsigned)hh < (unsigned)kH)
        v = fbase[((size_t)(ic0 + ic) * kH + hh) * kW + wcol];
      sm.a.in_s[ic][rr][c] = v;
    }
    // stage weights: w1[oc][ic0+ic][ky][kx] -> w_s[ic][k][oc]
    for (int idx = t; idx < 8 * 9 * 128; idx += 256) {
      int oc = idx & 127, q = idx >> 7, ic = q / 9, k = q % 9;
      sm.a.w_s[ic][k][oc] = w1[((size_t)oc * 128 + ic0 + ic) * 9 + k];
    }
    __syncthreads();
    #pragma unroll
    for (int ic = 0; ic < 8; ++ic) {
      #pragma unroll
      for (int ky = 0; ky < 3; ++ky) {
        const float* ip = &sm.a.in_s[ic][ky][pg * 4];
        double iv[6];
        { float4 v4 = ld4(ip);
          iv[0] = (double)v4.x; iv[1] = (double)v4.y;
          iv[2] = (double)v4.z; iv[3] = (double)v4.w;
          iv[4] = (double)ip[4]; iv[5] = (double)ip[5]; }
        #pragma unroll
        for (int kx = 0; kx < 3; ++kx) {
          const float* wp = &sm.a.w_s[ic][ky * 3 + kx][og * 8];
          float4 wA = ld4(wp), wB = ld4(wp + 4);
          double wv[8] = {(double)wA.x, (double)wA.y, (double)wA.z, (double)wA.w,
                          (double)wB.x, (double)wB.y, (double)wB.z, (double)wB.w};
          #pragma unroll
          for (int oi = 0; oi < 8; ++oi)
            #pragma unroll
            for (int pi = 0; pi < 4; ++pi)
              acc[oi][pi] = fma(wv[oi], iv[pi + kx], acc[oi][pi]);
        }
      }
    }
    __syncthreads();
  }

  // x = relu(conv + bias) in f64 -> LDS; stage cls weights
  #pragma unroll
  for (int oi = 0; oi < 8; ++oi) {
    int oc = og * 8 + oi;
    double bias = (double)b1[oc];
    #pragma unroll
    for (int pi = 0; pi < 4; ++pi)
      sm.b.x_s[oc][pg * 4 + pi] = fmax(acc[oi][pi] + bias, 0.0);
  }
  for (int idx = t; idx < 9 * 128; idx += 256) {
    int o = idx >> 7, c = idx & 127;
    sm.b.w9[o][c] = cw[o * 128 + c];
  }
  __syncthreads();

  // cls head: 9 outputs x 64 px, f64
  const int px = t & 63;
  const int g = t >> 6;            // wave-uniform
  const int oA = g, oB = g + 4;    // g0 also handles o=8
  double a0 = 0.0, a1 = 0.0, a2 = 0.0;
  for (int c = 0; c < 128; ++c) {
    double xv = sm.b.x_s[c][px];
    a0 = fma(xv, (double)sm.b.w9[oA][c], a0);
    a1 = fma(xv, (double)sm.b.w9[oB][c], a1);
    if (g == 0) a2 = fma(xv, (double)sm.b.w9[8][c], a2);
  }
  const int pxg = px0 + px;
  if (pxg < kW) {
    size_t base = (size_t)n * kM + ((size_t)h * kW + pxg) * 9;
    scores[base + oA] = a0 + (double)cb[oA];
    scores[base + oB] = a1 + (double)cb[oB];
    if (g == 0) scores[base + 8] = a2 + (double)cb[8];
  }
}

// ================= exact per-image top-6000 (f64 radix select) ========
__global__ __launch_bounds__(1024) void topk_kernel(
    const double* __restrict__ scores, unsigned* __restrict__ sidx,
    unsigned* __restrict__ eqbuf)
{
  const int img = blockIdx.x;
  const double* sc = scores + (size_t)img * kM;
  __shared__ unsigned hist[256];
  __shared__ uint64_t sh_prefix, sh_pmask;
  __shared__ unsigned sh_K, sh_cg, sh_ce, sh_ip, sh_im, sh_Ki, sh_pos;
  const int t = threadIdx.x;
  if (t == 0) { sh_prefix = 0; sh_pmask = 0; sh_K = kPre; }
  __syncthreads();
  for (int pass = 0; pass < 8; ++pass) {
    const int shift = 56 - pass * 8;
    if (t < 256) hist[t] = 0;
    __syncthreads();
    uint64_t prefix = sh_prefix, pmask = sh_pmask;
    for (int i = t; i < kM; i += 1024) {
      uint64_t u = ordd(sc[i]);
      if ((u & pmask) == prefix) atomicAdd(&hist[(unsigned)(u >> shift) & 255u], 1u);
    }
    __syncthreads();
    if (t == 0) {
      unsigned c = 0; int b = 255;
      for (; b > 0; --b) { unsigned hh = hist[b]; if (c + hh >= sh_K) break; c += hh; }
      sh_prefix |= ((uint64_t)(unsigned)b) << shift;
      sh_pmask  |= ((uint64_t)0xFFu) << shift;
      sh_K -= c;
    }
    __syncthreads();
  }
  const uint64_t T = sh_prefix;
  const unsigned need = sh_K;
  const unsigned ngt = kPre - need;
  if (t == 0) { sh_cg = 0; sh_ce = 0; }
  __syncthreads();
  unsigned* tout = sidx + (size_t)img * kPre;
  unsigned* eq = eqbuf + (size_t)img * 8192;
  for (int i = t; i < kM; i += 1024) {
    uint64_t u = ordd(sc[i]);
    if (u > T)      { unsigned p = atomicAdd(&sh_cg, 1u); tout[p] = (unsigned)i; }
    else if (u == T){ unsigned p = atomicAdd(&sh_ce, 1u); if (p < 8192u) eq[p] = (unsigned)i; }
  }
  __syncthreads();
  unsigned ce = sh_ce; if (ce > 8192u) ce = 8192u;
  if (ce == need) {
    for (unsigned j = t; j < need; j += 1024) tout[ngt + j] = eq[j];
    return;
  }
  // tie path (f64 ties ~impossible, kept for safety): need smallest indices
  if (t == 0) { sh_ip = 0; sh_im = 0; sh_Ki = need; sh_pos = 0; }
  __syncthreads();
  for (int pass = 0; pass < 3; ++pass) {
    const int shift = 12 - pass * 6;
    if (t < 64) hist[t] = 0;
    __syncthreads();
    unsigned prefix = sh_ip, pmask = sh_im;
    for (unsigned i = t; i < ce; i += 1024) {
      unsigned v = eq[i];
      if ((v & pmask) == prefix) atomicAdd(&hist[(v >> shift) & 63u], 1u);
    }
    __syncthreads();
    if (t == 0) {
      unsigned c = 0; int b = 0;
      for (; b < 63; ++b) { unsigned hh = hist[b]; if (c + hh >= sh_Ki) break; c += hh; }
      sh_ip |= ((unsigned)b) << shift;
      sh_im |= 63u << shift;
      sh_Ki -= c;
    }
    __syncthreads();
  }
  const unsigned tau = sh_ip;
  for (unsigned i = t; i < ce; i += 1024) {
    unsigned v = eq[i];
    if (v <= tau) { unsigned p = atomicAdd(&sh_pos, 1u); tout[ngt + p] = v; }
  }
}

// ========== bitonic sort of top-6000 by (f64 score desc, idx asc) =====
__global__ __launch_bounds__(1024) void sort_kernel(
    const double* __restrict__ scores, unsigned* __restrict__ sidx)
{
  const int img = blockIdx.x;
  const int t = threadIdx.x;
  __shared__ uint64_t k64[8192];   // 64 KB
  __shared__ unsigned id32[8192];  // 32 KB
  const double* sc = scores + (size_t)img * kM;
  unsigned* sp = sidx + (size_t)img * kPre;
  for (int j = t; j < 8192; j += 1024) {
    if (j < kPre) {
      unsigned idx = sp[j];
      k64[j] = ordd(sc[idx]);
      id32[j] = idx;
    } else { k64[j] = 0; id32[j] = 0xFFFFFFFFu; }
  }
  __syncthreads();
  for (unsigned kk = 2; kk <= 8192; kk <<= 1) {
    for (unsigned jj = kk >> 1; jj > 0; jj >>= 1) {
      for (unsigned i = t; i < 8192; i += 1024) {
        unsigned ixj = i ^ jj;
        if (ixj > i) {
          uint64_t ka = k64[i], kb = k64[ixj];
          unsigned ia = id32[i], ib = id32[ixj];
          bool desc = ((i & kk) == 0);
          bool amisplaced = (ka < kb) || (ka == kb && ia > ib); // a after b in desc
          if (desc ? amisplaced : !amisplaced) {
            k64[i] = kb; k64[ixj] = ka;
            id32[i] = ib; id32[ixj] = ia;
          }
        }
      }
      __syncthreads();
    }
  }
  for (int r = t; r < kPre; r += 1024) sp[r] = id32[r];
}

// ==== box head recompute (selected anchors only) + decode + clip ======
// grid (752, 8 imgs), 128 threads; each block handles 8 consecutive ranks.
__global__ __launch_bounds__(128) void box_kernel(
    const float* __restrict__ feat, const float* __restrict__ w1,
    const float* __restrict__ b1, const float* __restrict__ bwp,
    const float* __restrict__ bbp, const double* __restrict__ scores,
    const unsigned* __restrict__ sidx, const int* __restrict__ imgsz,
    double* __restrict__ cand)
{
  const int img = blockIdx.y;
  const int r0 = blockIdx.x * 8;
  const int t = threadIdx.x;
  double* cx1 = cand + (size_t)img * 6 * kCand;
  double* cy1 = cx1 + kCand; double* cx2 = cy1 + kCand; double* cy2 = cx2 + kCand;
  double* car = cy2 + kCand; double* csc = car + kCand;
  if (r0 >= kPre) {        // pad ranks [6000,6016)
    if (t < 8) {
      int r = r0 + t;
      cx1[r] = 0.0; cy1[r] = 0.0; cx2[r] = 0.0; cy2[r] = 0.0;
      car[r] = 0.0; csc[r] = -1e9;
    }
    return;
  }
  __shared__ float patch[8][1156];   // 36.9 KB
  __shared__ double xa[128][8];      // 8 KB
  __shared__ double dd[8][4];
  __shared__ unsigned meta[8];
  if (t < 8) meta[t] = sidx[(size_t)img * kPre + r0 + t];
  __syncthreads();
  const float* fb = feat + (size_t)img * 128 * kHW;
  for (int e = t; e < 8 * 384; e += 128) {
    int rr = e / 384, q = e % 384, ic = q / 3, ky = q % 3;
    unsigned idx = meta[rr];
    int pix = (int)(idx / 9u);
    int hh = pix / kW - 1 + ky, ww = pix % kW;
    float v0 = 0.f, v1 = 0.f, v2 = 0.f;
    if ((unsigned)hh < (unsigned)kH) {
      const float* row = fb + ((size_t)ic * kH + hh) * kW;
      if (ww - 1 >= 0) v0 = row[ww - 1];
      v1 = row[ww];
      if (ww + 1 < kW) v2 = row[ww + 1];
    }
    float* pp = &patch[rr][ic * 9 + ky * 3];
    pp[0] = v0; pp[1] = v1; pp[2] = v2;
  }
  __syncthreads();
  {
    const int oc = t;
    double a8[8] = {0, 0, 0, 0, 0, 0, 0, 0};
    const float* wrow = w1 + (size_t)oc * 1152;
    for (int j = 0; j < 1152; j += 4) {
      float4 wv = ld4(wrow + j);
      double w0 = (double)wv.x, w1d = (double)wv.y,
             w2 = (double)wv.z, w3 = (double)wv.w;
      #pragma unroll
      for (int rr = 0; rr < 8; ++rr) {
        float4 pv = ld4(&patch[rr][j]);
        a8[rr] = fma(w0, (double)pv.x, a8[rr]);
        a8[rr] = fma(w1d, (double)pv.y, a8[rr]);
        a8[rr] = fma(w2, (double)pv.z, a8[rr]);
        a8[rr] = fma(w3, (double)pv.w, a8[rr]);
      }
    }
    double bb1 = (double)b1[oc];
    #pragma unroll
    for (int rr = 0; rr < 8; ++rr) xa[oc][rr] = fmax(a8[rr] + bb1, 0.0);
  }
  __syncthreads();
  if (t < 32) {
    int rr = t >> 2, j = t & 3;
    unsigned idx = meta[rr];
    int a = (int)(idx % 9u);
    const float* wr = bwp + (size_t)(a * 4 + j) * 128;
    double acc = 0.0;
    for (int oc = 0; oc < 128; ++oc) acc = fma((double)wr[oc], xa[oc][rr], acc);
    dd[rr][j] = acc + (double)bbp[a * 4 + j];
  }
  __syncthreads();
  if (t < 8) {
    int r = r0 + t;
    unsigned idx = meta[t];
    int a = (int)(idx % 9u);
    int pix = (int)(idx / 9u);
    int hh = pix / kW, ww = pix % kW;
    double img_f = (double)imgsz[0];
    double stride = floor(img_f / (double)kW + 0.5);
    double sx = (double)ww * stride, sy = (double)hh * stride;
    double hwd = (double)c_hw[a], hhd = (double)c_hh[a];
    double a0 = sx - hwd, a1 = sy - hhd, a2 = sx + hwd, a3 = sy + hhd;
    double wa = a2 - a0, ha = a3 - a1;
    double cxa = a0 + 0.5 * wa, cya = a1 + 0.5 * ha;
    double dx = dd[t][0], dy = dd[t][1];
    double dw = fmin(dd[t][2], kClampD), dh = fmin(dd[t][3], kClampD);
    double cx = dx * wa + cxa, cy = dy * ha + cya;
    double bw2 = exp(dw) * wa, bh2 = exp(dh) * ha;
    double x1 = cx - 0.5 * bw2, y1 = cy - 0.5 * bh2;
    double x2 = cx + 0.5 * bw2, y2 = cy + 0.5 * bh2;
    x1 = fmin(fmax(x1, 0.0), img_f); y1 = fmin(fmax(y1, 0.0), img_f);
    x2 = fmin(fmax(x2, 0.0), img_f); y2 = fmin(fmax(y2, 0.0), img_f);
    cx1[r] = x1; cy1[r] = y1; cx2[r] = x2; cy2[r] = y2;
    car[r] = (x2 - x1) * (y2 - y1);
    csc[r] = scores[(size_t)img * kM + idx];
  }
}

// ================= NMS suppression bitmask (f64) =======================
__global__ __launch_bounds__(64) void mask_kernel(
    const double* __restrict__ cand, uint64_t* __restrict__ mask)
{
  const int img = blockIdx.z, bi = blockIdx.y, bj = blockIdx.x;
  const int i = bi * 64 + (int)threadIdx.x;
  const double* cx1 = cand + (size_t)img * 6 * kCand;
  const double* cy1 = cx1 + kCand; const double* cx2 = cy1 + kCand;
  const double* cy2 = cx2 + kCand; const double* car = cy2 + kCand;
  const double x1 = cx1[i], y1 = cy1[i], x2 = cx2[i], y2 = cy2[i], ar = car[i];
  uint64_t bits = 0;
  for (int jj = 0; jj < 64; ++jj) {
    const int j = bj * 64 + jj;
    double ix1 = fmax(x1, cx1[j]);
    double iy1 = fmax(y1, cy1[j]);
    double ix2 = fmin(x2, cx2[j]);
    double iy2 = fmin(y2, cy2[j]);
    double inter = fmax(ix2 - ix1, 0.0) * fmax(iy2 - iy1, 0.0);
    double denom = fmax(ar + car[j] - inter, 1e-9);
    // iou > 0.7  <=>  inter > 0.7*denom (denom > 0); flip prob ~1e-16, safe
    bits |= (uint64_t)(inter > 0.7 * denom) << jj;
  }
  mask[((size_t)img * kWords + bj) * kCand + i] = bits;
}

// ================= serial greedy scan + output =========================
__global__ __launch_bounds__(64) void scan_kernel(
    const double* __restrict__ cand, const uint64_t* __restrict__ mask,
    float* __restrict__ out)
{
  const int img = blockIdx.x;
  const int lane = (int)threadIdx.x;
  __shared__ uint64_t rem[kWords];
  __shared__ unsigned short keep[kPost];
  for (int w = lane; w < kWords; w += 64) rem[w] = 0;
  __syncthreads();
  const uint64_t* mb = mask + (size_t)img * kWords * kCand;
  int cnt = 0;
  for (int w64 = 0; w64 < kWords && cnt < kPost; ++w64) {
    uint64_t cur = rem[w64];
    const int bmax = (w64 == 93) ? 48 : 64;   // i < 6000
    for (int b = 0; b < bmax; ++b) {
      if ((cur >> b) & 1ull) continue;
      const int i = w64 * 64 + b;
      if (lane == 0) keep[cnt] = (unsigned short)i;
      ++cnt;
      if (cnt == kPost) break;
      for (int w = lane; w < kWords; w += 64) rem[w] |= mb[(size_t)w * kCand + i];
      __syncthreads();
      cur = rem[w64];
    }
  }
  __syncthreads();
  const double* cx1 = cand + (size_t)img * 6 * kCand;
  const double* cy1 = cx1 + kCand; const double* cx2 = cy1 + kCand;
  const double* cy2 = cx2 + kCand; const double* car = cy2 + kCand;
  const double* csc = car + kCand;
  for (int r = lane; r < kPost; r += 64) {
    float b0 = 0.f, b1 = 0.f, b2 = 0.f, b3 = 0.f, s = -1e9f;
    if (r < cnt) {
      int i = keep[r];
      b0 = (float)cx1[i]; b1 = (float)cy1[i];
      b2 = (float)cx2[i]; b3 = (float)cy2[i]; s = (float)csc[i];
    }
    float* ob = out + ((size_t)img * kPost + r) * 4;
    ob[0] = b0; ob[1] = b1; ob[2] = b2; ob[3] = b3;
    out[(size_t)kN * kPost * 4 + (size_t)img * kPost + r] = s;
  }
}

}  // namespace

extern "C" void kernel_launch(void* const* d_in, const int* in_sizes, int n_in,
                              void* d_out, int out_size, void* d_ws, size_t ws_size,
                              hipStream_t stream) {
  const float* feat = (const float*)d_in[0];
  const float* w1   = (const float*)d_in[1];
  const float* b1   = (const float*)d_in[2];
  const float* cw   = (const float*)d_in[3];
  const float* cb   = (const float*)d_in[4];
  const float* bwp  = (const float*)d_in[5];
  const float* bbp  = (const float*)d_in[6];
  const int*   imgsz = (const int*)d_in[7];
  float* out = (float*)d_out;
  char* ws = (char*)d_ws;
  if (ws_size < WS_NEED) return;

  double*   scores = (double*)(ws + OFF_SCORES);
  unsigned* sidx   = (unsigned*)(ws + OFF_SIDX);
  unsigned* eqb    = (unsigned*)(ws + OFF_EQ);
  double*   cand   = (double*)(ws + OFF_CAND);
  uint64_t* mask   = (uint64_t*)(ws + OFF_MASK);

  hipLaunchKernelGGL(conv_cls_kernel, dim3(3, kH, kN), dim3(256), 0, stream,
                     feat, w1, b1, cw, cb, scores);
  hipLaunchKernelGGL(topk_kernel, dim3(kN), dim3(1024), 0, stream,
                     scores, sidx, eqb);
  hipLaunchKernelGGL(sort_kernel, dim3(kN), dim3(1024), 0, stream,
                     scores, sidx);
  hipLaunchKernelGGL(box_kernel, dim3(kCand / 8, kN), dim3(128), 0, stream,
                     feat, w1, b1, bwp, bbp, scores, sidx, imgsz, cand);
  hipLaunchKernelGGL(mask_kernel, dim3(kWords, kWords, kN), dim3(64), 0, stream,
                     cand, mask);
  hipLaunchKernelGGL(scan_kernel, dim3(kN), dim3(64), 0, stream,
                     cand, mask, out);
}

// Round 5
// 4287.038 us; speedup vs baseline: 1.0077x; 1.0077x over previous
//
#include <hip/hip_runtime.h>
#include <stdint.h>
#include <math.h>

namespace {

constexpr int kH = 160, kW = 160, kN = 8;
constexpr int kHW = kH * kW;              // 25600
constexpr int kM = kHW * 9;               // 230400 anchors / image
constexpr int kPre = 6000;
constexpr int kPost = 1000;
constexpr int kCand = 6016;
constexpr int kWords = 94;                // ceil(6016/64)
constexpr int kRowW = 96;                 // padded words per mask row
constexpr double kClampD = 4.135166556742356;  // np.log(1000/16) in f64

// ---- workspace layout (bytes) ----
constexpr size_t OFF_SCORES = 0;
constexpr size_t SZ_SCORES  = (size_t)kN * kM * 8;                 // 14.75 MB (f64)
constexpr size_t OFF_SIDX   = OFF_SCORES + SZ_SCORES;
constexpr size_t SZ_SIDX    = (size_t)kN * kPre * 4;
constexpr size_t OFF_EQ     = OFF_SIDX + SZ_SIDX;
constexpr size_t SZ_EQ      = (size_t)kN * 8192 * 4;
constexpr size_t OFF_CAND   = OFF_EQ + SZ_EQ;
constexpr size_t SZ_CAND    = (size_t)kN * 6 * kCand * 8;          // f64
constexpr size_t OFF_MASK   = OFF_CAND + SZ_CAND;
constexpr size_t SZ_MASK    = (size_t)kN * kCand * kRowW * 8;      // 36.9 MB
constexpr size_t WS_NEED    = OFF_MASK + SZ_MASK;                  // ~54.5 MB

// base-anchor half extents (f32 of the f64 values, a = 3*size_idx + ratio_idx)
__constant__ float c_hw[9] = {
  22.627416997969522f, 16.0f, 11.313708498984761f,
  45.254833995939045f, 32.0f, 22.627416997969522f,
  90.509667991878090f, 64.0f, 45.254833995939045f};
__constant__ float c_hh[9] = {
  11.313708498984761f, 16.0f, 22.627416997969522f,
  22.627416997969522f, 32.0f, 45.254833995939045f,
  45.254833995939045f, 64.0f, 90.509667991878090f};

__device__ __forceinline__ uint64_t ordd(double d) {
  uint64_t u = (uint64_t)__double_as_longlong(d);
  return (u >> 63) ? ~u : (u | 0x8000000000000000ull);
}
__device__ __forceinline__ float4 ld4(const float* p) {
  return *reinterpret_cast<const float4*>(p);
}

// ballot-aggregated LDS histogram add (avoids same-address atomic serialization
// when buckets are exponent-clustered in the first radix passes)
__device__ __forceinline__ void hist_add(unsigned* hist, unsigned bucket, bool active) {
  uint64_t same = __ballot(active ? 1 : 0);
  #pragma unroll
  for (int b = 0; b < 8; ++b) {
    uint64_t bb = __ballot((bucket >> b) & 1u);
    same &= ((bucket >> b) & 1u) ? bb : ~bb;
  }
  if (active) {
    int lane = (int)(threadIdx.x & 63);
    int leader = __ffsll((unsigned long long)same) - 1;
    if (lane == leader) atomicAdd(&hist[bucket], (unsigned)__popcll((unsigned long long)same));
  }
}

// ================= fused conv3x3(f64 acc) + relu + cls head ===========
// grid (2 px-tiles of 80, 160 h, 8 n), 256 threads = 8 px-groups x 32 oc-groups.
// Thread owns 4 oc x 10 px. Inputs converted to f64 ONCE at staging; weights
// f32 in LDS, converted 4-at-a-time serving 40 FMA (10% cvt overhead).
struct SA { double in_d[8][3][84]; float w_s[72][132]; };   // 16128 + 38016 B
struct SB { double x_s[128][41]; float w9[9][128]; };       // 41984 + 4608 B
union SU { SA a; SB b; };

__global__ __launch_bounds__(256) void conv_cls_kernel(
    const float* __restrict__ feat, const float* __restrict__ w1,
    const float* __restrict__ b1, const float* __restrict__ cw,
    const float* __restrict__ cb,
    double* __restrict__ scores)
{
  __shared__ __align__(16) SU sm;
  const int bx = blockIdx.x, h = blockIdx.y, n = blockIdx.z;
  const int px0 = bx * 80;
  const int t = threadIdx.x;
  const int pg = t & 7, og = t >> 3;      // px-group (8), oc-group (32)
  const float* fbase = feat + (size_t)n * 128 * kHW;

  double acc[4][10];
  #pragma unroll
  for (int oi = 0; oi < 4; ++oi)
    #pragma unroll
    for (int pi = 0; pi < 10; ++pi) acc[oi][pi] = 0.0;

  for (int ic0 = 0; ic0 < 128; ic0 += 8) {
    __syncthreads();
    // stage input f64: 8 ic x 3 rows x 82 cols (col c -> w = px0-1+c)
    for (int idx = t; idx < 8 * 3 * 82; idx += 256) {
      int c = idx % 82, q = idx / 82, rr = q % 3, ic = q / 3;
      int wcol = px0 - 1 + c, hh = h - 1 + rr;
      float v = 0.f;
      if ((unsigned)wcol < (unsigned)kW && (unsigned)hh < (unsigned)kH)
        v = fbase[((size_t)(ic0 + ic) * kH + hh) * kW + wcol];
      sm.a.in_d[ic][rr][c] = (double)v;
    }
    // stage weights f32: w_s[ck][oc], ck = ic_local*9 + (ky*3+kx)
    for (int idx = t; idx < 9216; idx += 256) {
      int oc = idx / 72, ck = idx % 72;
      sm.a.w_s[ck][oc] = w1[(size_t)oc * 1152 + (size_t)ic0 * 9 + ck];
    }
    __syncthreads();
    for (int ic = 0; ic < 8; ++ic) {
      #pragma unroll
      for (int ky = 0; ky < 3; ++ky) {
        const double* ip = &sm.a.in_d[ic][ky][pg * 10];
        double iv[12];
        #pragma unroll
        for (int q = 0; q < 6; ++q) {
          double2 v2 = *reinterpret_cast<const double2*>(ip + 2 * q);
          iv[2 * q] = v2.x; iv[2 * q + 1] = v2.y;
        }
        #pragma unroll
        for (int kx = 0; kx < 3; ++kx) {
          float4 wv = ld4(&sm.a.w_s[ic * 9 + ky * 3 + kx][og * 4]);
          double wd[4] = {(double)wv.x, (double)wv.y, (double)wv.z, (double)wv.w};
          #pragma unroll
          for (int oi = 0; oi < 4; ++oi)
            #pragma unroll
            for (int pi = 0; pi < 10; ++pi)
              acc[oi][pi] = fma(wd[oi], iv[pi + kx], acc[oi][pi]);
        }
      }
    }
  }

  // cls head in two 40-px halves (x_s too big for all 80 px at good occupancy)
  double bias[4];
  #pragma unroll
  for (int oi = 0; oi < 4; ++oi) bias[oi] = (double)b1[og * 4 + oi];
  for (int hf = 0; hf < 2; ++hf) {
    __syncthreads();   // prior phase's LDS reads complete
    if ((pg >> 2) == hf) {
      int col0 = (pg & 3) * 10;
      #pragma unroll
      for (int oi = 0; oi < 4; ++oi)
        #pragma unroll
        for (int pi = 0; pi < 10; ++pi)
          sm.b.x_s[og * 4 + oi][col0 + pi] = fmax(acc[oi][pi] + bias[oi], 0.0);
    }
    if (hf == 0)
      for (int idx = t; idx < 1152; idx += 256)
        sm.b.w9[idx >> 7][idx & 127] = cw[idx];
    __syncthreads();
    for (int idx = t; idx < 360; idx += 256) {
      int o = idx / 40, px = idx % 40;
      double s = 0.0;
      for (int c = 0; c < 128; ++c)
        s = fma(sm.b.x_s[c][px], (double)sm.b.w9[o][c], s);
      s += (double)cb[o];
      int col = px0 + hf * 40 + px;
      scores[(size_t)n * kM + ((size_t)h * kW + col) * 9 + o] = s;
    }
  }
}

// ================= exact per-image top-6000 (f64 radix select) ========
__global__ __launch_bounds__(1024) void topk_kernel(
    const double* __restrict__ scores, unsigned* __restrict__ sidx,
    unsigned* __restrict__ eqbuf)
{
  const int img = blockIdx.x;
  const double* sc = scores + (size_t)img * kM;
  __shared__ unsigned hist[256];
  __shared__ uint64_t sh_prefix, sh_pmask;
  __shared__ unsigned sh_K, sh_cg, sh_ce, sh_ip, sh_im, sh_Ki, sh_pos;
  const int t = threadIdx.x;
  if (t == 0) { sh_prefix = 0; sh_pmask = 0; sh_K = kPre; }
  __syncthreads();
  for (int pass = 0; pass < 8; ++pass) {
    const int shift = 56 - pass * 8;
    if (t < 256) hist[t] = 0;
    __syncthreads();
    uint64_t prefix = sh_prefix, pmask = sh_pmask;
    for (int i = t; i < kM; i += 1024) {          // kM % 1024 == 0: no divergence
      uint64_t u = ordd(sc[i]);
      bool active = ((u & pmask) == prefix);
      hist_add(hist, (unsigned)(u >> shift) & 255u, active);
    }
    __syncthreads();
    if (t == 0) {
      unsigned c = 0; int b = 255;
      for (; b > 0; --b) { unsigned hh = hist[b]; if (c + hh >= sh_K) break; c += hh; }
      sh_prefix |= ((uint64_t)(unsigned)b) << shift;
      sh_pmask  |= ((uint64_t)0xFFu) << shift;
      sh_K -= c;
    }
    __syncthreads();
  }
  const uint64_t T = sh_prefix;
  const unsigned need = sh_K;
  const unsigned ngt = kPre - need;
  if (t == 0) { sh_cg = 0; sh_ce = 0; }
  __syncthreads();
  unsigned* tout = sidx + (size_t)img * kPre;
  unsigned* eq = eqbuf + (size_t)img * 8192;
  for (int i = t; i < kM; i += 1024) {
    uint64_t u = ordd(sc[i]);
    if (u > T)      { unsigned p = atomicAdd(&sh_cg, 1u); tout[p] = (unsigned)i; }
    else if (u == T){ unsigned p = atomicAdd(&sh_ce, 1u); if (p < 8192u) eq[p] = (unsigned)i; }
  }
  __syncthreads();
  unsigned ce = sh_ce; if (ce > 8192u) ce = 8192u;
  if (ce == need) {
    for (unsigned j = t; j < need; j += 1024) tout[ngt + j] = eq[j];
    return;
  }
  // tie path (f64 exact ties ~impossible; safety): take `need` smallest indices
  if (t == 0) { sh_ip = 0; sh_im = 0; sh_Ki = need; sh_pos = 0; }
  __syncthreads();
  for (int pass = 0; pass < 3; ++pass) {
    const int shift = 12 - pass * 6;
    if (t < 64) hist[t] = 0;
    __syncthreads();
    unsigned prefix = sh_ip, pmask = sh_im;
    for (unsigned i = t; i < ce; i += 1024) {
      unsigned v = eq[i];
      if ((v & pmask) == prefix) atomicAdd(&hist[(v >> shift) & 63u], 1u);
    }
    __syncthreads();
    if (t == 0) {
      unsigned c = 0; int b = 0;
      for (; b < 63; ++b) { unsigned hh = hist[b]; if (c + hh >= sh_Ki) break; c += hh; }
      sh_ip |= ((unsigned)b) << shift;
      sh_im |= 63u << shift;
      sh_Ki -= c;
    }
    __syncthreads();
  }
  const unsigned tau = sh_ip;
  for (unsigned i = t; i < ce; i += 1024) {
    unsigned v = eq[i];
    if (v <= tau) { unsigned p = atomicAdd(&sh_pos, 1u); tout[ngt + p] = v; }
  }
}

// ========== bitonic sort of top-6000 by (f64 score desc, idx asc) =====
__global__ __launch_bounds__(1024) void sort_kernel(
    const double* __restrict__ scores, unsigned* __restrict__ sidx)
{
  const int img = blockIdx.x;
  const int t = threadIdx.x;
  __shared__ uint64_t k64[8192];   // 64 KB
  __shared__ unsigned id32[8192];  // 32 KB
  const double* sc = scores + (size_t)img * kM;
  unsigned* sp = sidx + (size_t)img * kPre;
  for (int j = t; j < 8192; j += 1024) {
    if (j < kPre) {
      unsigned idx = sp[j];
      k64[j] = ordd(sc[idx]);
      id32[j] = idx;
    } else { k64[j] = 0; id32[j] = 0xFFFFFFFFu; }
  }
  __syncthreads();
  for (unsigned kk = 2; kk <= 8192; kk <<= 1) {
    for (unsigned jj = kk >> 1; jj > 0; jj >>= 1) {
      for (unsigned i = t; i < 8192; i += 1024) {
        unsigned ixj = i ^ jj;
        if (ixj > i) {
          uint64_t ka = k64[i], kb = k64[ixj];
          unsigned ia = id32[i], ib = id32[ixj];
          bool desc = ((i & kk) == 0);
          bool amisplaced = (ka < kb) || (ka == kb && ia > ib);
          if (desc ? amisplaced : !amisplaced) {
            k64[i] = kb; k64[ixj] = ka;
            id32[i] = ib; id32[ixj] = ia;
          }
        }
      }
      __syncthreads();
    }
  }
  for (int r = t; r < kPre; r += 1024) sp[r] = id32[r];
}

// ==== box head recompute (selected anchors only) + decode + clip ======
__global__ __launch_bounds__(128) void box_kernel(
    const float* __restrict__ feat, const float* __restrict__ w1,
    const float* __restrict__ b1, const float* __restrict__ bwp,
    const float* __restrict__ bbp, const double* __restrict__ scores,
    const unsigned* __restrict__ sidx, const int* __restrict__ imgsz,
    double* __restrict__ cand)
{
  const int img = blockIdx.y;
  const int r0 = blockIdx.x * 8;
  const int t = threadIdx.x;
  double* cx1 = cand + (size_t)img * 6 * kCand;
  double* cy1 = cx1 + kCand; double* cx2 = cy1 + kCand; double* cy2 = cx2 + kCand;
  double* car = cy2 + kCand; double* csc = car + kCand;
  if (r0 >= kPre) {
    if (t < 8) {
      int r = r0 + t;
      cx1[r] = 0.0; cy1[r] = 0.0; cx2[r] = 0.0; cy2[r] = 0.0;
      car[r] = 0.0; csc[r] = -1e9;
    }
    return;
  }
  __shared__ float patch[8][1156];
  __shared__ double xa[128][8];
  __shared__ double dd[8][4];
  __shared__ unsigned meta[8];
  if (t < 8) meta[t] = sidx[(size_t)img * kPre + r0 + t];
  __syncthreads();
  const float* fb = feat + (size_t)img * 128 * kHW;
  for (int e = t; e < 8 * 384; e += 128) {
    int rr = e / 384, q = e % 384, ic = q / 3, ky = q % 3;
    unsigned idx = meta[rr];
    int pix = (int)(idx / 9u);
    int hh = pix / kW - 1 + ky, ww = pix % kW;
    float v0 = 0.f, v1 = 0.f, v2 = 0.f;
    if ((unsigned)hh < (unsigned)kH) {
      const float* row = fb + ((size_t)ic * kH + hh) * kW;
      if (ww - 1 >= 0) v0 = row[ww - 1];
      v1 = row[ww];
      if (ww + 1 < kW) v2 = row[ww + 1];
    }
    float* pp = &patch[rr][ic * 9 + ky * 3];
    pp[0] = v0; pp[1] = v1; pp[2] = v2;
  }
  __syncthreads();
  {
    const int oc = t;
    double a8[8] = {0, 0, 0, 0, 0, 0, 0, 0};
    const float* wrow = w1 + (size_t)oc * 1152;
    for (int j = 0; j < 1152; j += 4) {
      float4 wv = ld4(wrow + j);
      double w0 = (double)wv.x, w1d = (double)wv.y,
             w2 = (double)wv.z, w3 = (double)wv.w;
      #pragma unroll
      for (int rr = 0; rr < 8; ++rr) {
        float4 pv = ld4(&patch[rr][j]);
        a8[rr] = fma(w0, (double)pv.x, a8[rr]);
        a8[rr] = fma(w1d, (double)pv.y, a8[rr]);
        a8[rr] = fma(w2, (double)pv.z, a8[rr]);
        a8[rr] = fma(w3, (double)pv.w, a8[rr]);
      }
    }
    double bb1 = (double)b1[oc];
    #pragma unroll
    for (int rr = 0; rr < 8; ++rr) xa[oc][rr] = fmax(a8[rr] + bb1, 0.0);
  }
  __syncthreads();
  if (t < 32) {
    int rr = t >> 2, j = t & 3;
    unsigned idx = meta[rr];
    int a = (int)(idx % 9u);
    const float* wr = bwp + (size_t)(a * 4 + j) * 128;
    double acc = 0.0;
    for (int oc = 0; oc < 128; ++oc) acc = fma((double)wr[oc], xa[oc][rr], acc);
    dd[rr][j] = acc + (double)bbp[a * 4 + j];
  }
  __syncthreads();
  if (t < 8) {
    int r = r0 + t;
    unsigned idx = meta[t];
    int a = (int)(idx % 9u);
    int pix = (int)(idx / 9u);
    int hh = pix / kW, ww = pix % kW;
    double img_f = (double)imgsz[0];
    double stride = floor(img_f / (double)kW + 0.5);
    double sx = (double)ww * stride, sy = (double)hh * stride;
    double hwd = (double)c_hw[a], hhd = (double)c_hh[a];
    double a0 = sx - hwd, a1 = sy - hhd, a2 = sx + hwd, a3 = sy + hhd;
    double wa = a2 - a0, ha = a3 - a1;
    double cxa = a0 + 0.5 * wa, cya = a1 + 0.5 * ha;
    double dx = dd[t][0], dy = dd[t][1];
    double dw = fmin(dd[t][2], kClampD), dh = fmin(dd[t][3], kClampD);
    double cx = dx * wa + cxa, cy = dy * ha + cya;
    double bw2 = exp(dw) * wa, bh2 = exp(dh) * ha;
    double x1 = cx - 0.5 * bw2, y1 = cy - 0.5 * bh2;
    double x2 = cx + 0.5 * bw2, y2 = cy + 0.5 * bh2;
    x1 = fmin(fmax(x1, 0.0), img_f); y1 = fmin(fmax(y1, 0.0), img_f);
    x2 = fmin(fmax(x2, 0.0), img_f); y2 = fmin(fmax(y2, 0.0), img_f);
    cx1[r] = x1; cy1[r] = y1; cx2[r] = x2; cy2[r] = y2;
    car[r] = (x2 - x1) * (y2 - y1);
    csc[r] = scores[(size_t)img * kM + idx];
  }
}

// ================= NMS suppression bitmask (row-major) =================
// grid (12 word-octets, 94 row-blocks, 8 imgs), 64 threads (one row each).
// Each lane computes 8 consecutive words of its row -> one 64B line store.
__global__ __launch_bounds__(64) void mask_kernel(
    const double* __restrict__ cand, uint64_t* __restrict__ mask)
{
  const int img = blockIdx.z, bi = blockIdx.y, b8 = blockIdx.x;
  const int i = bi * 64 + (int)threadIdx.x;
  const double* cx1 = cand + (size_t)img * 6 * kCand;
  const double* cy1 = cx1 + kCand; const double* cx2 = cy1 + kCand;
  const double* cy2 = cx2 + kCand; const double* car = cy2 + kCand;
  const double x1 = cx1[i], y1 = cy1[i], x2 = cx2[i], y2 = cy2[i], ar = car[i];
  uint64_t row[8];
  #pragma unroll
  for (int wi = 0; wi < 8; ++wi) {
    const int w = b8 * 8 + wi;
    uint64_t bits = 0;
    if (w < kWords) {
      const int j0 = w * 64;
      for (int jj = 0; jj < 64; ++jj) {
        const int j = j0 + jj;
        double ix1 = fmax(x1, cx1[j]);
        double iy1 = fmax(y1, cy1[j]);
        double ix2 = fmin(x2, cx2[j]);
        double iy2 = fmin(y2, cy2[j]);
        double inter = fmax(ix2 - ix1, 0.0) * fmax(iy2 - iy1, 0.0);
        double denom = fmax(ar + car[j] - inter, 1e-9);
        bits |= (uint64_t)(inter > 0.7 * denom) << jj;
      }
    }
    row[wi] = bits;
  }
  uint64_t* rp = mask + ((size_t)img * kCand + i) * kRowW + b8 * 8;
  #pragma unroll
  for (int wi = 0; wi < 8; ++wi)
    if (b8 * 8 + wi < kWords) rp[wi] = row[wi];
}

// ================= serial greedy scan + output =========================
__global__ __launch_bounds__(64) void scan_kernel(
    const double* __restrict__ cand, const uint64_t* __restrict__ mask,
    float* __restrict__ out)
{
  const int img = blockIdx.x;
  const int lane = (int)threadIdx.x;
  __shared__ uint64_t rem[kWords];
  __shared__ unsigned short keep[kPost];
  for (int w = lane; w < kWords; w += 64) rem[w] = 0;
  __syncthreads();
  const uint64_t* mb = mask + (size_t)img * kCand * kRowW;
  int cnt = 0;
  for (int w64 = 0; w64 < kWords && cnt < kPost; ++w64) {
    uint64_t cur = rem[w64];
    const int bmax = (w64 == 93) ? 48 : 64;   // i < 6000
    for (int b = 0; b < bmax; ++b) {
      if ((cur >> b) & 1ull) continue;
      const int i = w64 * 64 + b;
      if (lane == 0) keep[cnt] = (unsigned short)i;
      ++cnt;
      if (cnt == kPost) break;
      const uint64_t* ri = mb + (size_t)i * kRowW;
      for (int w = lane; w < kWords; w += 64) rem[w] |= ri[w];
      __syncthreads();
      cur = rem[w64];
    }
  }
  __syncthreads();
  const double* cx1 = cand + (size_t)img * 6 * kCand;
  const double* cy1 = cx1 + kCand; const double* cx2 = cy1 + kCand;
  const double* cy2 = cx2 + kCand; const double* car = cy2 + kCand;
  const double* csc = car + kCand;
  for (int r = lane; r < kPost; r += 64) {
    float b0 = 0.f, b1v = 0.f, b2 = 0.f, b3 = 0.f, s = -1e9f;
    if (r < cnt) {
      int i = keep[r];
      b0 = (float)cx1[i]; b1v = (float)cy1[i];
      b2 = (float)cx2[i]; b3 = (float)cy2[i]; s = (float)csc[i];
    }
    float* ob = out + ((size_t)img * kPost + r) * 4;
    ob[0] = b0; ob[1] = b1v; ob[2] = b2; ob[3] = b3;
    out[(size_t)kN * kPost * 4 + (size_t)img * kPost + r] = s;
  }
}

}  // namespace

extern "C" void kernel_launch(void* const* d_in, const int* in_sizes, int n_in,
                              void* d_out, int out_size, void* d_ws, size_t ws_size,
                              hipStream_t stream) {
  const float* feat = (const float*)d_in[0];
  const float* w1   = (const float*)d_in[1];
  const float* b1   = (const float*)d_in[2];
  const float* cw   = (const float*)d_in[3];
  const float* cb   = (const float*)d_in[4];
  const float* bwp  = (const float*)d_in[5];
  const float* bbp  = (const float*)d_in[6];
  const int*   imgsz = (const int*)d_in[7];
  float* out = (float*)d_out;
  char* ws = (char*)d_ws;
  if (ws_size < WS_NEED) return;

  double*   scores = (double*)(ws + OFF_SCORES);
  unsigned* sidx   = (unsigned*)(ws + OFF_SIDX);
  unsigned* eqb    = (unsigned*)(ws + OFF_EQ);
  double*   cand   = (double*)(ws + OFF_CAND);
  uint64_t* mask   = (uint64_t*)(ws + OFF_MASK);

  hipLaunchKernelGGL(conv_cls_kernel, dim3(2, kH, kN), dim3(256), 0, stream,
                     feat, w1, b1, cw, cb, scores);
  hipLaunchKernelGGL(topk_kernel, dim3(kN), dim3(1024), 0, stream,
                     scores, sidx, eqb);
  hipLaunchKernelGGL(sort_kernel, dim3(kN), dim3(1024), 0, stream,
                     scores, sidx);
  hipLaunchKernelGGL(box_kernel, dim3(kCand / 8, kN), dim3(128), 0, stream,
                     feat, w1, b1, bwp, bbp, scores, sidx, imgsz, cand);
  hipLaunchKernelGGL(mask_kernel, dim3(12, kWords, kN), dim3(64), 0, stream,
                     cand, mask);
  hipLaunchKernelGGL(scan_kernel, dim3(kN), dim3(64), 0, stream,
                     cand, mask, out);
}

// Round 6
// 3623.042 us; speedup vs baseline: 1.1923x; 1.1833x over previous
//
#include <hip/hip_runtime.h>
#include <stdint.h>
#include <math.h>

namespace {

constexpr int kH = 160, kW = 160, kN = 8;
constexpr int kHW = kH * kW;              // 25600
constexpr int kM = kHW * 9;               // 230400 anchors / image
constexpr int kPre = 6000;
constexpr int kPost = 1000;
constexpr int kCand = 6016;
constexpr int kWords = 94;                // ceil(6016/64)
constexpr int kRowW = 96;                 // padded words per mask row
constexpr double kClampD = 4.135166556742356;  // np.log(1000/16) in f64

// base-anchor half extents — f32 values (reference rounds base anchors to f32
// via np.array(base, np.float32); everything downstream upcasts to f64).
// DO NOT change to f64 — round 4 verified bit-exact with this exact path.
__constant__ float c_hw[9] = {
  22.627416997969522f, 16.0f, 11.313708498984761f,
  45.254833995939045f, 32.0f, 22.627416997969522f,
  90.509667991878090f, 64.0f, 45.254833995939045f};
__constant__ float c_hh[9] = {
  11.313708498984761f, 16.0f, 22.627416997969522f,
  22.627416997969522f, 32.0f, 45.254833995939045f,
  45.254833995939045f, 64.0f, 90.509667991878090f};

__device__ __forceinline__ uint64_t ordd(double d) {
  uint64_t u = (uint64_t)__double_as_longlong(d);
  return (u >> 63) ? ~u : (u | 0x8000000000000000ull);
}
__device__ __forceinline__ float4 ld4(const float* p) {
  return *reinterpret_cast<const float4*>(p);
}

__device__ __forceinline__ void hist_add(unsigned* hist, unsigned bucket, bool active) {
  uint64_t same = __ballot(active ? 1 : 0);
  #pragma unroll
  for (int b = 0; b < 8; ++b) {
    uint64_t bb = __ballot((bucket >> b) & 1u);
    same &= ((bucket >> b) & 1u) ? bb : ~bb;
  }
  if (active) {
    int lane = (int)(threadIdx.x & 63);
    int leader = __ffsll((unsigned long long)same) - 1;
    if (lane == leader) atomicAdd(&hist[bucket], (unsigned)__popcll((unsigned long long)same));
  }
}

// ============ weight transpose prep: wT[R][oc] = w1[oc][R], R=ic*9+k =======
__global__ __launch_bounds__(256) void prep_kernel(
    const float* __restrict__ w1, float* __restrict__ wT)
{
  int i = blockIdx.x * 256 + (int)threadIdx.x;   // i = R*128 + oc
  if (i < 1152 * 128) {
    int R = i >> 7, oc = i & 127;
    wT[i] = w1[(size_t)oc * 1152 + R];
  }
}

// ====== fused conv3x3(f64) + relu + cls head (9) [+ box head (36)] ========
// grid (2 px-tiles of 80, 160 h, 8 n), 256 thr = 8 px-groups x 32 oc-groups.
struct SA { double in_d[8][3][84]; float w_s[72][128]; };  // 16128 + 36864 = 52992
struct SB { double x_s[128][21]; float w45[45][129]; };    // 21504 + 23220 = 44724
union SU { SA a; SB b; };

__global__ __launch_bounds__(256) void conv_heads_kernel(
    const float* __restrict__ feat, const float* __restrict__ wT,
    const float* __restrict__ b1, const float* __restrict__ cw,
    const float* __restrict__ cb, const float* __restrict__ bw,
    const float* __restrict__ bb,
    double* __restrict__ scores, double* __restrict__ dout)
{
  __shared__ __align__(16) SU sm;
  const int bx = blockIdx.x, h = blockIdx.y, n = blockIdx.z;
  const int px0 = bx * 80;
  const int t = threadIdx.x;
  const int pg = t & 7, og = t >> 3;      // px-group (8 x 10px), oc-group (32 x 4oc)
  const float* fbase = feat + (size_t)n * 128 * kHW;

  double acc[4][10];
  #pragma unroll
  for (int oi = 0; oi < 4; ++oi)
    #pragma unroll
    for (int pi = 0; pi < 10; ++pi) acc[oi][pi] = 0.0;

  for (int ic0 = 0; ic0 < 128; ic0 += 8) {
    __syncthreads();
    // stage input f64: 8 ic x 3 rows x 82 cols (col c -> w = px0-1+c)
    for (int idx = t; idx < 1968; idx += 256) {
      int c = idx % 82, q2 = idx / 82, rr = q2 % 3, ic = q2 / 3;
      int wcol = px0 - 1 + c, hh2 = h - 1 + rr;
      float v = 0.f;
      if ((unsigned)wcol < (unsigned)kW && (unsigned)hh2 < (unsigned)kH)
        v = fbase[((size_t)(ic0 + ic) * kH + hh2) * kW + wcol];
      sm.a.in_d[ic][rr][c] = (double)v;
    }
    // stage weights from pre-transposed wT: stride-1 writes (conflict-free)
    for (int idx = t; idx < 9216; idx += 256) {
      int oc = idx & 127, ck = idx >> 7;
      sm.a.w_s[ck][oc] = wT[(size_t)(ic0 * 9 + ck) * 128 + oc];
    }
    __syncthreads();
    for (int ic = 0; ic < 8; ++ic) {
      #pragma unroll
      for (int ky = 0; ky < 3; ++ky) {
        const double* ip = &sm.a.in_d[ic][ky][pg * 10];
        double iv[12];
        #pragma unroll
        for (int q2 = 0; q2 < 6; ++q2) {
          double2 v2 = *reinterpret_cast<const double2*>(ip + 2 * q2);
          iv[2 * q2] = v2.x; iv[2 * q2 + 1] = v2.y;
        }
        #pragma unroll
        for (int kx = 0; kx < 3; ++kx) {
          float4 wv = ld4(&sm.a.w_s[ic * 9 + ky * 3 + kx][og * 4]);
          double wd[4] = {(double)wv.x, (double)wv.y, (double)wv.z, (double)wv.w};
          #pragma unroll
          for (int oi = 0; oi < 4; ++oi)
            #pragma unroll
            for (int pi = 0; pi < 10; ++pi)
              acc[oi][pi] = fma(wd[oi], iv[pi + kx], acc[oi][pi]);
        }
      }
    }
  }

  // heads in 4 phases of 20 px (keeps union LDS <= 53KB -> 3 blocks/CU)
  double bias[4];
  #pragma unroll
  for (int oi = 0; oi < 4; ++oi) bias[oi] = (double)b1[og * 4 + oi];
  const int nOut = dout ? 45 : 9;
  for (int q = 0; q < 4; ++q) {
    __syncthreads();
    if ((pg >> 1) == q) {
      int col0 = (pg & 1) * 10;
      #pragma unroll
      for (int oi = 0; oi < 4; ++oi)
        #pragma unroll
        for (int pi = 0; pi < 10; ++pi)
          sm.b.x_s[og * 4 + oi][col0 + pi] = fmax(acc[oi][pi] + bias[oi], 0.0);
    }
    if (q == 0) {
      for (int idx = t; idx < 45 * 128; idx += 256) {
        int o = idx >> 7, c = idx & 127;
        sm.b.w45[o][c] = (o < 9) ? cw[o * 128 + c] : bw[(o - 9) * 128 + c];
      }
    }
    __syncthreads();
    const int ndots = nOut * 20;
    for (int idx = t; idx < ndots; idx += 256) {
      int o = idx / 20, pl = idx % 20;
      const float* wr = sm.b.w45[o];
      double s = 0.0;
      for (int c = 0; c < 128; ++c)
        s = fma(sm.b.x_s[c][pl], (double)wr[c], s);
      int pxg = px0 + q * 20 + pl;
      size_t abase = (size_t)n * kM + ((size_t)h * kW + pxg) * 9;
      if (o < 9) {
        scores[abase + o] = s + (double)cb[o];
      } else {
        int ob = o - 9;
        dout[(abase + (ob >> 2)) * 4 + (ob & 3)] = s + (double)bb[ob];
      }
    }
  }
}

// ================= exact per-image top-6000 (f64 radix select) ========
__global__ __launch_bounds__(1024) void topk_kernel(
    const double* __restrict__ scores, unsigned* __restrict__ sidx,
    unsigned* __restrict__ eqbuf)
{
  const int img = blockIdx.x;
  const double* sc = scores + (size_t)img * kM;
  __shared__ unsigned hist[256];
  __shared__ uint64_t sh_prefix, sh_pmask;
  __shared__ unsigned sh_K, sh_cg, sh_ce, sh_ip, sh_im, sh_Ki, sh_pos;
  const int t = threadIdx.x;
  if (t == 0) { sh_prefix = 0; sh_pmask = 0; sh_K = kPre; }
  __syncthreads();
  for (int pass = 0; pass < 8; ++pass) {
    const int shift = 56 - pass * 8;
    if (t < 256) hist[t] = 0;
    __syncthreads();
    uint64_t prefix = sh_prefix, pmask = sh_pmask;
    for (int i = t; i < kM; i += 1024) {
      uint64_t u = ordd(sc[i]);
      bool active = ((u & pmask) == prefix);
      hist_add(hist, (unsigned)(u >> shift) & 255u, active);
    }
    __syncthreads();
    if (t == 0) {
      unsigned c = 0; int b = 255;
      for (; b > 0; --b) { unsigned hh = hist[b]; if (c + hh >= sh_K) break; c += hh; }
      sh_prefix |= ((uint64_t)(unsigned)b) << shift;
      sh_pmask  |= ((uint64_t)0xFFu) << shift;
      sh_K -= c;
    }
    __syncthreads();
  }
  const uint64_t T = sh_prefix;
  const unsigned need = sh_K;
  const unsigned ngt = kPre - need;
  if (t == 0) { sh_cg = 0; sh_ce = 0; }
  __syncthreads();
  unsigned* tout = sidx + (size_t)img * kPre;
  unsigned* eq = eqbuf + (size_t)img * 8192;
  for (int i = t; i < kM; i += 1024) {
    uint64_t u = ordd(sc[i]);
    if (u > T)      { unsigned p = atomicAdd(&sh_cg, 1u); tout[p] = (unsigned)i; }
    else if (u == T){ unsigned p = atomicAdd(&sh_ce, 1u); if (p < 8192u) eq[p] = (unsigned)i; }
  }
  __syncthreads();
  unsigned ce = sh_ce; if (ce > 8192u) ce = 8192u;
  if (ce == need) {
    for (unsigned j = t; j < need; j += 1024) tout[ngt + j] = eq[j];
    return;
  }
  if (t == 0) { sh_ip = 0; sh_im = 0; sh_Ki = need; sh_pos = 0; }
  __syncthreads();
  for (int pass = 0; pass < 3; ++pass) {
    const int shift = 12 - pass * 6;
    if (t < 64) hist[t] = 0;
    __syncthreads();
    unsigned prefix = sh_ip, pmask = sh_im;
    for (unsigned i = t; i < ce; i += 1024) {
      unsigned v = eq[i];
      if ((v & pmask) == prefix) atomicAdd(&hist[(v >> shift) & 63u], 1u);
    }
    __syncthreads();
    if (t == 0) {
      unsigned c = 0; int b = 0;
      for (; b < 63; ++b) { unsigned hh = hist[b]; if (c + hh >= sh_Ki) break; c += hh; }
      sh_ip |= ((unsigned)b) << shift;
      sh_im |= 63u << shift;
      sh_Ki -= c;
    }
    __syncthreads();
  }
  const unsigned tau = sh_ip;
  for (unsigned i = t; i < ce; i += 1024) {
    unsigned v = eq[i];
    if (v <= tau) { unsigned p = atomicAdd(&sh_pos, 1u); tout[ngt + p] = v; }
  }
}

// ==== bitonic sort (score desc, idx asc) + optional decode from deltas ====
__global__ __launch_bounds__(1024) void sort_decode_kernel(
    const double* __restrict__ scores, const double* __restrict__ deltas,
    unsigned* __restrict__ sidx, const int* __restrict__ imgsz,
    double* __restrict__ cand)
{
  const int img = blockIdx.x;
  const int t = threadIdx.x;
  __shared__ uint64_t k64[8192];
  __shared__ unsigned id32[8192];
  const double* sc = scores + (size_t)img * kM;
  unsigned* sp = sidx + (size_t)img * kPre;
  for (int j = t; j < 8192; j += 1024) {
    if (j < kPre) {
      unsigned idx = sp[j];
      k64[j] = ordd(sc[idx]);
      id32[j] = idx;
    } else { k64[j] = 0; id32[j] = 0xFFFFFFFFu; }
  }
  __syncthreads();
  for (unsigned kk = 2; kk <= 8192; kk <<= 1) {
    for (unsigned jj = kk >> 1; jj > 0; jj >>= 1) {
      for (unsigned i = t; i < 8192; i += 1024) {
        unsigned ixj = i ^ jj;
        if (ixj > i) {
          uint64_t ka = k64[i], kb = k64[ixj];
          unsigned ia = id32[i], ib = id32[ixj];
          bool desc = ((i & kk) == 0);
          bool amis = (ka < kb) || (ka == kb && ia > ib);
          if (desc ? amis : !amis) {
            k64[i] = kb; k64[ixj] = ka;
            id32[i] = ib; id32[ixj] = ia;
          }
        }
      }
      __syncthreads();
    }
  }
  for (int r = t; r < kPre; r += 1024) sp[r] = id32[r];
  if (!deltas) return;
  // decode path (deltas precomputed by conv)
  double* cx1 = cand + (size_t)img * 6 * kCand;
  double* cy1 = cx1 + kCand; double* cx2 = cy1 + kCand; double* cy2 = cx2 + kCand;
  double* car = cy2 + kCand; double* csc = car + kCand;
  const double img_f = (double)imgsz[0];
  const double stride = floor(img_f / (double)kW + 0.5);
  for (int r = t; r < kCand; r += 1024) {
    if (r < kPre) {
      unsigned idx = id32[r];
      int a = (int)(idx % 9u);
      int pix = (int)(idx / 9u);
      int hh = pix / kW, ww = pix % kW;
      double sx = (double)ww * stride, sy = (double)hh * stride;
      double hwd = (double)c_hw[a], hhd = (double)c_hh[a];
      double a0 = sx - hwd, a1 = sy - hhd, a2 = sx + hwd, a3 = sy + hhd;
      double wa = a2 - a0, ha = a3 - a1;
      double cxa = a0 + 0.5 * wa, cya = a1 + 0.5 * ha;
      const double* d = deltas + ((size_t)img * kM + idx) * 4;
      double dx = d[0], dy = d[1];
      double dw = fmin(d[2], kClampD), dh = fmin(d[3], kClampD);
      double cx = dx * wa + cxa, cy = dy * ha + cya;
      double bw2 = exp(dw) * wa, bh2 = exp(dh) * ha;
      double x1 = cx - 0.5 * bw2, y1 = cy - 0.5 * bh2;
      double x2 = cx + 0.5 * bw2, y2 = cy + 0.5 * bh2;
      x1 = fmin(fmax(x1, 0.0), img_f); y1 = fmin(fmax(y1, 0.0), img_f);
      x2 = fmin(fmax(x2, 0.0), img_f); y2 = fmin(fmax(y2, 0.0), img_f);
      cx1[r] = x1; cy1[r] = y1; cx2[r] = x2; cy2[r] = y2;
      car[r] = (x2 - x1) * (y2 - y1);
      csc[r] = sc[idx];
    } else {
      cx1[r] = 0.0; cy1[r] = 0.0; cx2[r] = 0.0; cy2[r] = 0.0;
      car[r] = 0.0; csc[r] = -1e9;
    }
  }
}

// ==== box head recompute fallback (small-ws path; verified in round 4/5) ===
__global__ __launch_bounds__(128) void box_kernel(
    const float* __restrict__ feat, const float* __restrict__ w1,
    const float* __restrict__ b1, const float* __restrict__ bwp,
    const float* __restrict__ bbp, const double* __restrict__ scores,
    const unsigned* __restrict__ sidx, const int* __restrict__ imgsz,
    double* __restrict__ cand)
{
  const int img = blockIdx.y;
  const int r0 = blockIdx.x * 8;
  const int t = threadIdx.x;
  double* cx1 = cand + (size_t)img * 6 * kCand;
  double* cy1 = cx1 + kCand; double* cx2 = cy1 + kCand; double* cy2 = cx2 + kCand;
  double* car = cy2 + kCand; double* csc = car + kCand;
  if (r0 >= kPre) {
    if (t < 8) {
      int r = r0 + t;
      cx1[r] = 0.0; cy1[r] = 0.0; cx2[r] = 0.0; cy2[r] = 0.0;
      car[r] = 0.0; csc[r] = -1e9;
    }
    return;
  }
  __shared__ float patch[8][1156];
  __shared__ double xa[128][8];
  __shared__ double dd[8][4];
  __shared__ unsigned meta[8];
  if (t < 8) meta[t] = sidx[(size_t)img * kPre + r0 + t];
  __syncthreads();
  const float* fb = feat + (size_t)img * 128 * kHW;
  for (int e = t; e < 8 * 384; e += 128) {
    int rr = e / 384, q = e % 384, ic = q / 3, ky = q % 3;
    unsigned idx = meta[rr];
    int pix = (int)(idx / 9u);
    int hh = pix / kW - 1 + ky, ww = pix % kW;
    float v0 = 0.f, v1 = 0.f, v2 = 0.f;
    if ((unsigned)hh < (unsigned)kH) {
      const float* row = fb + ((size_t)ic * kH + hh) * kW;
      if (ww - 1 >= 0) v0 = row[ww - 1];
      v1 = row[ww];
      if (ww + 1 < kW) v2 = row[ww + 1];
    }
    float* pp = &patch[rr][ic * 9 + ky * 3];
    pp[0] = v0; pp[1] = v1; pp[2] = v2;
  }
  __syncthreads();
  {
    const int oc = t;
    double a8[8] = {0, 0, 0, 0, 0, 0, 0, 0};
    const float* wrow = w1 + (size_t)oc * 1152;
    for (int j = 0; j < 1152; j += 4) {
      float4 wv = ld4(wrow + j);
      double w0 = (double)wv.x, w1d = (double)wv.y,
             w2 = (double)wv.z, w3 = (double)wv.w;
      #pragma unroll
      for (int rr = 0; rr < 8; ++rr) {
        float4 pv = ld4(&patch[rr][j]);
        a8[rr] = fma(w0, (double)pv.x, a8[rr]);
        a8[rr] = fma(w1d, (double)pv.y, a8[rr]);
        a8[rr] = fma(w2, (double)pv.z, a8[rr]);
        a8[rr] = fma(w3, (double)pv.w, a8[rr]);
      }
    }
    double bb1 = (double)b1[oc];
    #pragma unroll
    for (int rr = 0; rr < 8; ++rr) xa[oc][rr] = fmax(a8[rr] + bb1, 0.0);
  }
  __syncthreads();
  if (t < 32) {
    int rr = t >> 2, j = t & 3;
    unsigned idx = meta[rr];
    int a = (int)(idx % 9u);
    const float* wr = bwp + (size_t)(a * 4 + j) * 128;
    double acc = 0.0;
    for (int oc = 0; oc < 128; ++oc) acc = fma((double)wr[oc], xa[oc][rr], acc);
    dd[rr][j] = acc + (double)bbp[a * 4 + j];
  }
  __syncthreads();
  if (t < 8) {
    int r = r0 + t;
    unsigned idx = meta[t];
    int a = (int)(idx % 9u);
    int pix = (int)(idx / 9u);
    int hh = pix / kW, ww = pix % kW;
    double img_f = (double)imgsz[0];
    double stride = floor(img_f / (double)kW + 0.5);
    double sx = (double)ww * stride, sy = (double)hh * stride;
    double hwd = (double)c_hw[a], hhd = (double)c_hh[a];
    double a0 = sx - hwd, a1 = sy - hhd, a2 = sx + hwd, a3 = sy + hhd;
    double wa = a2 - a0, ha = a3 - a1;
    double cxa = a0 + 0.5 * wa, cya = a1 + 0.5 * ha;
    double dx = dd[t][0], dy = dd[t][1];
    double dw = fmin(dd[t][2], kClampD), dh = fmin(dd[t][3], kClampD);
    double cx = dx * wa + cxa, cy = dy * ha + cya;
    double bw2 = exp(dw) * wa, bh2 = exp(dh) * ha;
    double x1 = cx - 0.5 * bw2, y1 = cy - 0.5 * bh2;
    double x2 = cx + 0.5 * bw2, y2 = cy + 0.5 * bh2;
    x1 = fmin(fmax(x1, 0.0), img_f); y1 = fmin(fmax(y1, 0.0), img_f);
    x2 = fmin(fmax(x2, 0.0), img_f); y2 = fmin(fmax(y2, 0.0), img_f);
    cx1[r] = x1; cy1[r] = y1; cx2[r] = x2; cy2[r] = y2;
    car[r] = (x2 - x1) * (y2 - y1);
    csc[r] = scores[(size_t)img * kM + idx];
  }
}

// ============ NMS suppression bitmask (row-major, upper triangle) ==========
// grid (12 word-octets, 94 row-blocks, 8 imgs), 64 threads (one row each).
// Octets entirely below the diagonal are skipped: those bits are never
// consulted by the scan (only j > i matters), so garbage there is harmless.
__global__ __launch_bounds__(64) void mask_kernel(
    const double* __restrict__ cand, uint64_t* __restrict__ mask)
{
  const int img = blockIdx.z, bi = blockIdx.y, b8 = blockIdx.x;
  if (bi >= (b8 + 1) * 8) return;   // all j in octet < all i in block
  const int i = bi * 64 + (int)threadIdx.x;
  const double* cx1 = cand + (size_t)img * 6 * kCand;
  const double* cy1 = cx1 + kCand; const double* cx2 = cy1 + kCand;
  const double* cy2 = cx2 + kCand; const double* car = cy2 + kCand;
  __shared__ double jb[5][512];
  const int j0base = b8 * 512;
  for (int e = (int)threadIdx.x; e < 512; e += 64) {
    int j = j0base + e;
    jb[0][e] = cx1[j]; jb[1][e] = cy1[j]; jb[2][e] = cx2[j];
    jb[3][e] = cy2[j]; jb[4][e] = car[j];
  }
  __syncthreads();
  const double x1 = cx1[i], y1 = cy1[i], x2 = cx2[i], y2 = cy2[i], ar = car[i];
  uint64_t row[8];
  #pragma unroll
  for (int wi = 0; wi < 8; ++wi) {
    const int w = b8 * 8 + wi;
    uint64_t bits = 0;
    if (w < kWords) {
      const int e0 = wi * 64;
      for (int jj = 0; jj < 64; ++jj) {
        const int e = e0 + jj;
        double ix1 = fmax(x1, jb[0][e]);
        double iy1 = fmax(y1, jb[1][e]);
        double ix2 = fmin(x2, jb[2][e]);
        double iy2 = fmin(y2, jb[3][e]);
        double inter = fmax(ix2 - ix1, 0.0) * fmax(iy2 - iy1, 0.0);
        double denom = fmax(ar + jb[4][e] - inter, 1e-9);
        bits |= (uint64_t)(inter > 0.7 * denom) << jj;
      }
    }
    row[wi] = bits;
  }
  uint64_t* rp = mask + ((size_t)img * kCand + i) * kRowW + b8 * 8;
  #pragma unroll
  for (int wi = 0; wi < 8; ++wi)
    if (b8 * 8 + wi < kWords) rp[wi] = row[wi];
}

// ===== serial greedy scan, depth-3 speculative row prefetch + output ======
__global__ __launch_bounds__(64) void scan_kernel(
    const double* __restrict__ cand, const uint64_t* __restrict__ mask,
    float* __restrict__ out)
{
  const int img = blockIdx.x;
  const int lane = (int)threadIdx.x;
  __shared__ uint64_t rem[kWords];
  __shared__ unsigned short keep[kPost];
  for (int w = lane; w < kWords; w += 64) rem[w] = 0;
  __syncthreads();
  const uint64_t* mb = mask + (size_t)img * kCand * kRowW;

  auto loadrow = [&](int row, uint64_t& lo, uint64_t& hi) {
    const uint64_t* r = mb + (size_t)row * kRowW;
    lo = r[lane];
    hi = (lane + 64 < kWords) ? r[lane + 64] : 0ull;
  };
  auto next_clear = [&](int j) -> int {
    int w0 = j >> 6;
    uint64_t v = ~rem[lane];
    if (lane < w0) v = 0;
    else if (lane == w0) v &= ~((2ull << (j & 63)) - 1ull);
    if (lane == kWords - 1) v &= (1ull << 48) - 1ull;   // kPre = 93*64+48
    uint64_t ball = __ballot(v != 0ull);
    if (ball) {
      int L = __ffsll((unsigned long long)ball) - 1;
      uint64_t vv = __shfl(v, L);
      return L * 64 + __ffsll((unsigned long long)vv) - 1;
    }
    int w2 = lane + 64;
    uint64_t v2 = (w2 < kWords) ? ~rem[w2] : 0ull;
    if (w2 < w0) v2 = 0;
    else if (w2 == w0) v2 &= ~((2ull << (j & 63)) - 1ull);
    if (w2 == kWords - 1) v2 &= (1ull << 48) - 1ull;
    uint64_t ball2 = __ballot(v2 != 0ull);
    if (ball2) {
      int L = __ffsll((unsigned long long)ball2) - 1;
      uint64_t vv = __shfl(v2, L);
      return (L + 64) * 64 + __ffsll((unsigned long long)vv) - 1;
    }
    return kPre;
  };

  int cnt = 0;
  int j0 = 0, j1 = 1, j2 = 2;
  uint64_t aLo, aHi, bLo, bHi, cLo, cHi;
  loadrow(0, aLo, aHi);
  loadrow(1, bLo, bHi);
  loadrow(2, cLo, cHi);
  while (true) {
    if (lane == 0) keep[cnt] = (unsigned short)j0;
    ++cnt;
    if (cnt >= kPost) break;
    rem[lane] |= aLo;
    if (lane + 64 < kWords) rem[lane + 64] |= aHi;
    __syncthreads();
    int jr = next_clear(j0);          // authoritative next keep
    if (jr >= kPre) break;
    if (jr != j1) { j1 = jr; loadrow(j1, bLo, bHi); }
    int j2p = next_clear(j1);         // prediction (missing row j1's bits)
    if (j2p != j2) { j2 = j2p; if (j2 < kPre) loadrow(j2, cLo, cHi); }
    int j3 = (j2 < kPre) ? next_clear(j2) : kPre;
    uint64_t dLo = 0, dHi = 0;
    if (j3 < kPre) loadrow(j3, dLo, dHi);
    aLo = bLo; aHi = bHi; bLo = cLo; bHi = cHi; cLo = dLo; cHi = dHi;
    j0 = j1; j1 = j2; j2 = j3;
    __syncthreads();
  }
  __syncthreads();
  const double* cx1 = cand + (size_t)img * 6 * kCand;
  const double* cy1 = cx1 + kCand; const double* cx2 = cy1 + kCand;
  const double* cy2 = cx2 + kCand; const double* car = cy2 + kCand;
  const double* csc = car + kCand;
  for (int r = lane; r < kPost; r += 64) {
    float b0 = 0.f, b1v = 0.f, b2 = 0.f, b3 = 0.f, s = -1e9f;
    if (r < cnt) {
      int i = keep[r];
      b0 = (float)cx1[i]; b1v = (float)cy1[i];
      b2 = (float)cx2[i]; b3 = (float)cy2[i]; s = (float)csc[i];
    }
    float* ob = out + ((size_t)img * kPost + r) * 4;
    ob[0] = b0; ob[1] = b1v; ob[2] = b2; ob[3] = b3;
    out[(size_t)kN * kPost * 4 + (size_t)img * kPost + r] = s;
  }
}

}  // namespace

extern "C" void kernel_launch(void* const* d_in, const int* in_sizes, int n_in,
                              void* d_out, int out_size, void* d_ws, size_t ws_size,
                              hipStream_t stream) {
  const float* feat = (const float*)d_in[0];
  const float* w1   = (const float*)d_in[1];
  const float* b1   = (const float*)d_in[2];
  const float* cw   = (const float*)d_in[3];
  const float* cb   = (const float*)d_in[4];
  const float* bwp  = (const float*)d_in[5];
  const float* bbp  = (const float*)d_in[6];
  const int*   imgsz = (const int*)d_in[7];
  float* out = (float*)d_out;
  char* ws = (char*)d_ws;

  size_t off = 0;
  auto take = [&](size_t sz) { size_t o = off; off += (sz + 255) & ~(size_t)255; return o; };
  size_t oWT     = take((size_t)1152 * 128 * 4);
  size_t oScores = take((size_t)kN * kM * 8);
  size_t oSidx   = take((size_t)kN * kPre * 4);
  size_t oEq     = take((size_t)kN * 8192 * 4);
  size_t oCand   = take((size_t)kN * 6 * kCand * 8);
  size_t oMask   = take((size_t)kN * kCand * kRowW * 8);
  size_t baseNeed = off;
  size_t oDelt   = take((size_t)kN * kM * 4 * 8);
  size_t fullNeed = off;
  if (ws_size < baseNeed) return;
  const bool big = (ws_size >= fullNeed);

  float*    wT     = (float*)(ws + oWT);
  double*   scores = (double*)(ws + oScores);
  unsigned* sidx   = (unsigned*)(ws + oSidx);
  unsigned* eqb    = (unsigned*)(ws + oEq);
  double*   cand   = (double*)(ws + oCand);
  uint64_t* mask   = (uint64_t*)(ws + oMask);
  double*   deltas = big ? (double*)(ws + oDelt) : nullptr;

  hipLaunchKernelGGL(prep_kernel, dim3(576), dim3(256), 0, stream, w1, wT);
  hipLaunchKernelGGL(conv_heads_kernel, dim3(2, kH, kN), dim3(256), 0, stream,
                     feat, wT, b1, cw, cb, bwp, bbp, scores, deltas);
  hipLaunchKernelGGL(topk_kernel, dim3(kN), dim3(1024), 0, stream,
                     scores, sidx, eqb);
  hipLaunchKernelGGL(sort_decode_kernel, dim3(kN), dim3(1024), 0, stream,
                     scores, deltas, sidx, imgsz, cand);
  if (!big) {
    hipLaunchKernelGGL(box_kernel, dim3(kCand / 8, kN), dim3(128), 0, stream,
                       feat, w1, b1, bwp, bbp, scores, sidx, imgsz, cand);
  }
  hipLaunchKernelGGL(mask_kernel, dim3(12, kWords, kN), dim3(64), 0, stream,
                     cand, mask);
  hipLaunchKernelGGL(scan_kernel, dim3(kN), dim3(64), 0, stream,
                     cand, mask, out);
}

// Round 7
// 3502.199 us; speedup vs baseline: 1.2335x; 1.0345x over previous
//
#include <hip/hip_runtime.h>
#include <stdint.h>
#include <math.h>

namespace {

constexpr int kH = 160, kW = 160, kN = 8;
constexpr int kHW = kH * kW;              // 25600
constexpr int kM = kHW * 9;               // 230400 anchors / image
constexpr int kPre = 6000;
constexpr int kPost = 1000;
constexpr int kCand = 6016;
constexpr int kScr = 6144;                // f32-screen candidates (superset margin 144)
constexpr int kWords = 94;                // ceil(6016/64)
constexpr int kRowW = 96;                 // padded words per mask row
constexpr double kClampD = 4.135166556742356;  // np.log(1000/16) in f64

// base-anchor half extents — f32 values (reference rounds base anchors to f32);
// round 4 verified bit-exact with this path. DO NOT change.
__constant__ float c_hw[9] = {
  22.627416997969522f, 16.0f, 11.313708498984761f,
  45.254833995939045f, 32.0f, 22.627416997969522f,
  90.509667991878090f, 64.0f, 45.254833995939045f};
__constant__ float c_hh[9] = {
  11.313708498984761f, 16.0f, 22.627416997969522f,
  22.627416997969522f, 32.0f, 45.254833995939045f,
  45.254833995939045f, 64.0f, 90.509667991878090f};

__device__ __forceinline__ uint64_t ordd(double d) {
  uint64_t u = (uint64_t)__double_as_longlong(d);
  return (u >> 63) ? ~u : (u | 0x8000000000000000ull);
}
__device__ __forceinline__ unsigned ordf(float f) {
  unsigned u = __float_as_uint(f);
  return (u & 0x80000000u) ? ~u : (u | 0x80000000u);
}
__device__ __forceinline__ float4 ld4(const float* p) {
  return *reinterpret_cast<const float4*>(p);
}

__device__ __forceinline__ void hist_add(unsigned* hist, unsigned bucket, bool active) {
  uint64_t same = __ballot(active ? 1 : 0);
  #pragma unroll
  for (int b = 0; b < 8; ++b) {
    uint64_t bb = __ballot((bucket >> b) & 1u);
    same &= ((bucket >> b) & 1u) ? bb : ~bb;
  }
  if (active) {
    int lane = (int)(threadIdx.x & 63);
    int leader = __ffsll((unsigned long long)same) - 1;
    if (lane == leader) atomicAdd(&hist[bucket], (unsigned)__popcll((unsigned long long)same));
  }
}

// ============ weight transpose prep: wT[R][oc] = w1[oc][R], R=ic*9+k =======
__global__ __launch_bounds__(256) void prep_kernel(
    const float* __restrict__ w1, float* __restrict__ wT)
{
  int i = blockIdx.x * 256 + (int)threadIdx.x;
  if (i < 1152 * 128) {
    int R = i >> 7, oc = i & 127;
    wT[i] = w1[(size_t)oc * 1152 + R];
  }
}

// ========== f32 SCREEN: conv3x3 + relu + cls head (9 outputs) =============
// grid (2 px-tiles of 80, 160 h, 8 n), 256 thr = 8 px-groups x 32 oc-groups.
// f32 everywhere: only used to select top-6144 candidates (error budget 2.8e-4,
// actual f32 error ~1e-6 -> guaranteed superset of f64 top-6000).
struct SAf { float in_s[8][3][84]; float w_s[72][128]; };  // 8064 + 36864
struct SBf { float x_s[128][82]; float w9[9][128]; };      // 41984 + 4608
union SUf { SAf a; SBf b; };

__global__ __launch_bounds__(256) void conv_screen_kernel(
    const float* __restrict__ feat, const float* __restrict__ wT,
    const float* __restrict__ b1, const float* __restrict__ cw,
    const float* __restrict__ cb, float* __restrict__ scoresF)
{
  __shared__ __align__(16) SUf sm;
  const int bx = blockIdx.x, h = blockIdx.y, n = blockIdx.z;
  const int px0 = bx * 80;
  const int t = threadIdx.x;
  const int pg = t & 7, og = t >> 3;
  const float* fbase = feat + (size_t)n * 128 * kHW;

  float acc[4][10];
  #pragma unroll
  for (int oi = 0; oi < 4; ++oi)
    #pragma unroll
    for (int pi = 0; pi < 10; ++pi) acc[oi][pi] = 0.f;

  for (int ic0 = 0; ic0 < 128; ic0 += 8) {
    __syncthreads();
    for (int idx = t; idx < 1968; idx += 256) {
      int c = idx % 82, q2 = idx / 82, rr = q2 % 3, ic = q2 / 3;
      int wcol = px0 - 1 + c, hh2 = h - 1 + rr;
      float v = 0.f;
      if ((unsigned)wcol < (unsigned)kW && (unsigned)hh2 < (unsigned)kH)
        v = fbase[((size_t)(ic0 + ic) * kH + hh2) * kW + wcol];
      sm.a.in_s[ic][rr][c] = v;
    }
    for (int idx = t; idx < 9216; idx += 256) {
      int oc = idx & 127, ck = idx >> 7;
      sm.a.w_s[ck][oc] = wT[(size_t)(ic0 * 9 + ck) * 128 + oc];
    }
    __syncthreads();
    for (int ic = 0; ic < 8; ++ic) {
      #pragma unroll
      for (int ky = 0; ky < 3; ++ky) {
        const float* ip = &sm.a.in_s[ic][ky][pg * 10];   // 8B-aligned (pg*10 even)
        float iv[12];
        #pragma unroll
        for (int q2 = 0; q2 < 6; ++q2) {
          float2 v2 = *reinterpret_cast<const float2*>(ip + 2 * q2);
          iv[2 * q2] = v2.x; iv[2 * q2 + 1] = v2.y;
        }
        #pragma unroll
        for (int kx = 0; kx < 3; ++kx) {
          float4 wv = ld4(&sm.a.w_s[ic * 9 + ky * 3 + kx][og * 4]);
          float wd[4] = {wv.x, wv.y, wv.z, wv.w};
          #pragma unroll
          for (int oi = 0; oi < 4; ++oi)
            #pragma unroll
            for (int pi = 0; pi < 10; ++pi)
              acc[oi][pi] = fmaf(wd[oi], iv[pi + kx], acc[oi][pi]);
        }
      }
    }
  }

  __syncthreads();
  // x = relu(conv+bias) -> LDS (all 80 px), stage cls weights
  #pragma unroll
  for (int oi = 0; oi < 4; ++oi) {
    int oc = og * 4 + oi;
    float bias = b1[oc];
    #pragma unroll
    for (int pi = 0; pi < 10; ++pi)
      sm.b.x_s[oc][pg * 10 + pi] = fmaxf(acc[oi][pi] + bias, 0.f);
  }
  for (int idx = t; idx < 1152; idx += 256)
    sm.b.w9[idx >> 7][idx & 127] = cw[idx];
  __syncthreads();
  for (int idx = t; idx < 720; idx += 256) {
    int o = idx / 80, px = idx % 80;
    float s = 0.f;
    for (int c = 0; c < 128; ++c)
      s = fmaf(sm.b.x_s[c][px], sm.b.w9[o][c], s);
    scoresF[(size_t)n * kM + ((size_t)h * kW + px0 + px) * 9 + o] = s + cb[o];
  }
}

// ============ f32 radix top-6144 per image (candidate screen) =============
__global__ __launch_bounds__(1024) void screen_kernel(
    const float* __restrict__ scoresF, unsigned* __restrict__ candIdx,
    unsigned* __restrict__ eqbuf)
{
  const int img = blockIdx.x;
  const float* sc = scoresF + (size_t)img * kM;
  __shared__ unsigned hist[256];
  __shared__ unsigned sh_prefix, sh_pmask, sh_K, sh_cg, sh_ce, sh_ip, sh_im, sh_Ki, sh_pos;
  const int t = threadIdx.x;
  if (t == 0) { sh_prefix = 0; sh_pmask = 0; sh_K = kScr; }
  __syncthreads();
  for (int pass = 0; pass < 4; ++pass) {
    const int shift = 24 - pass * 8;
    if (t < 256) hist[t] = 0;
    __syncthreads();
    unsigned prefix = sh_prefix, pmask = sh_pmask;
    for (int i = t; i < kM; i += 1024) {
      unsigned u = ordf(sc[i]);
      bool active = ((u & pmask) == prefix);
      unsigned b = (u >> shift) & 255u;
      if (pass == 0) hist_add(hist, b, active);
      else if (active) atomicAdd(&hist[b], 1u);
    }
    __syncthreads();
    if (t == 0) {
      unsigned c = 0; int b = 255;
      for (; b > 0; --b) { unsigned hh = hist[b]; if (c + hh >= sh_K) break; c += hh; }
      sh_prefix |= ((unsigned)b) << shift;
      sh_pmask  |= 0xFFu << shift;
      sh_K -= c;
    }
    __syncthreads();
  }
  const unsigned T = sh_prefix;
  const unsigned need = sh_K;
  const unsigned ngt = kScr - need;
  if (t == 0) { sh_cg = 0; sh_ce = 0; }
  __syncthreads();
  unsigned* tout = candIdx + (size_t)img * kScr;
  unsigned* eq = eqbuf + (size_t)img * 8192;
  for (int i = t; i < kM; i += 1024) {
    unsigned u = ordf(sc[i]);
    if (u > T)      { unsigned p = atomicAdd(&sh_cg, 1u); tout[p] = (unsigned)i; }
    else if (u == T){ unsigned p = atomicAdd(&sh_ce, 1u); if (p < 8192u) eq[p] = (unsigned)i; }
  }
  __syncthreads();
  unsigned ce = sh_ce; if (ce > 8192u) ce = 8192u;
  if (ce == need) {
    for (unsigned j = t; j < need; j += 1024) tout[ngt + j] = eq[j];
    return;
  }
  // tie path: take `need` smallest indices among eq (18-bit indices, 3x6-bit)
  if (t == 0) { sh_ip = 0; sh_im = 0; sh_Ki = need; sh_pos = 0; }
  __syncthreads();
  for (int pass = 0; pass < 3; ++pass) {
    const int shift = 12 - pass * 6;
    if (t < 64) hist[t] = 0;
    __syncthreads();
    unsigned prefix = sh_ip, pmask = sh_im;
    for (unsigned i = t; i < ce; i += 1024) {
      unsigned v = eq[i];
      if ((v & pmask) == prefix) atomicAdd(&hist[(v >> shift) & 63u], 1u);
    }
    __syncthreads();
    if (t == 0) {
      unsigned c = 0; int b = 0;
      for (; b < 63; ++b) { unsigned hh = hist[b]; if (c + hh >= sh_Ki) break; c += hh; }
      sh_ip |= ((unsigned)b) << shift;
      sh_im |= 63u << shift;
      sh_Ki -= c;
    }
    __syncthreads();
  }
  const unsigned tau = sh_ip;
  for (unsigned i = t; i < ce; i += 1024) {
    unsigned v = eq[i];
    if (v <= tau) { unsigned p = atomicAdd(&sh_pos, 1u); tout[ngt + p] = v; }
  }
}

// ==== f64 refine: recompute x-column + 9->1 score + 4 deltas per candidate ==
// grid (kScr/4, 8 imgs), 128 threads. Patches staged as f64 (cvt at staging).
__global__ __launch_bounds__(128) void refine_kernel(
    const float* __restrict__ feat, const float* __restrict__ wT,
    const float* __restrict__ b1, const float* __restrict__ cw,
    const float* __restrict__ cb, const float* __restrict__ bwp,
    const float* __restrict__ bbp, const unsigned* __restrict__ candIdx,
    double* __restrict__ rsc, double* __restrict__ rdd)
{
  const int img = blockIdx.y;
  const int s0 = blockIdx.x * 4;
  const int t = threadIdx.x;
  __shared__ double patch[4][1160];   // 37.1 KB
  __shared__ double xa[128][4];       // 4 KB
  __shared__ double dd[4][5];
  __shared__ unsigned meta[4];
  if (t < 4) meta[t] = candIdx[(size_t)img * kScr + s0 + t];
  __syncthreads();
  const float* fb = feat + (size_t)img * 128 * kHW;
  for (int e = t; e < 4 * 384; e += 128) {
    int rr = e / 384, q = e % 384, ic = q / 3, ky = q % 3;
    unsigned idx = meta[rr];
    int pix = (int)(idx / 9u);
    int hh = pix / kW - 1 + ky, ww = pix % kW;
    float v0 = 0.f, v1 = 0.f, v2 = 0.f;
    if ((unsigned)hh < (unsigned)kH) {
      const float* row = fb + ((size_t)ic * kH + hh) * kW;
      if (ww - 1 >= 0) v0 = row[ww - 1];
      v1 = row[ww];
      if (ww + 1 < kW) v2 = row[ww + 1];
    }
    double* pp = &patch[rr][ic * 9 + ky * 3];
    pp[0] = (double)v0; pp[1] = (double)v1; pp[2] = (double)v2;
  }
  __syncthreads();
  {
    // oc = t: 4 candidate dots of length 1152, 2 partial sums each for ILP
    double aE[4] = {0, 0, 0, 0}, aO[4] = {0, 0, 0, 0};
    for (int R = 0; R < 1152; R += 2) {
      double w0 = (double)wT[(size_t)R * 128 + t];
      double w1d = (double)wT[(size_t)(R + 1) * 128 + t];
      #pragma unroll
      for (int rr = 0; rr < 4; ++rr) {
        aE[rr] = fma(w0, patch[rr][R], aE[rr]);
        aO[rr] = fma(w1d, patch[rr][R + 1], aO[rr]);
      }
    }
    double bb1 = (double)b1[t];
    #pragma unroll
    for (int rr = 0; rr < 4; ++rr)
      xa[t][rr] = fmax((aE[rr] + aO[rr]) + bb1, 0.0);
  }
  __syncthreads();
  if (t < 20) {
    int rr = t & 3, j = t >> 2;   // j in 0..4 (4 deltas + 1 score)
    unsigned idx = meta[rr];
    int a = (int)(idx % 9u);
    const float* wr = (j < 4) ? (bwp + (size_t)(a * 4 + j) * 128)
                              : (cw + (size_t)a * 128);
    double acc = 0.0;
    for (int c = 0; c < 128; ++c) acc = fma((double)wr[c], xa[c][rr], acc);
    dd[rr][j] = acc + (double)((j < 4) ? bbp[a * 4 + j] : cb[a]);
  }
  __syncthreads();
  if (t < 4) {
    size_t s = (size_t)img * kScr + s0 + t;
    rsc[s] = dd[t][4];
    double* rd = rdd + s * 4;
    rd[0] = dd[t][0]; rd[1] = dd[t][1]; rd[2] = dd[t][2]; rd[3] = dd[t][3];
  }
}

// == exact top-6000 select + sort (f64 desc, anchor-idx asc) + decode ======
__global__ __launch_bounds__(1024) void select_sort_decode_kernel(
    const double* __restrict__ rsc, const double* __restrict__ rdd,
    const unsigned* __restrict__ candIdx, const int* __restrict__ imgsz,
    double* __restrict__ cand)
{
  const int img = blockIdx.x;
  const int t = threadIdx.x;
  __shared__ uint64_t k64[8192];
  __shared__ unsigned id32[8192];   // (anchorIdx<<13) | slot
  for (int j = t; j < 8192; j += 1024) {
    if (j < kScr) {
      k64[j] = ordd(rsc[(size_t)img * kScr + j]);
      id32[j] = (candIdx[(size_t)img * kScr + j] << 13) | (unsigned)j;
    } else { k64[j] = 0; id32[j] = 0xFFFFFFFFu; }
  }
  __syncthreads();
  for (unsigned kk = 2; kk <= 8192; kk <<= 1) {
    for (unsigned jj = kk >> 1; jj > 0; jj >>= 1) {
      for (unsigned i = t; i < 8192; i += 1024) {
        unsigned ixj = i ^ jj;
        if (ixj > i) {
          uint64_t ka = k64[i], kb = k64[ixj];
          unsigned ia = id32[i], ib = id32[ixj];
          bool desc = ((i & kk) == 0);
          bool amis = (ka < kb) || (ka == kb && ia > ib);
          if (desc ? amis : !amis) {
            k64[i] = kb; k64[ixj] = ka;
            id32[i] = ib; id32[ixj] = ia;
          }
        }
      }
      __syncthreads();
    }
  }
  double* cx1 = cand + (size_t)img * 6 * kCand;
  double* cy1 = cx1 + kCand; double* cx2 = cy1 + kCand; double* cy2 = cx2 + kCand;
  double* car = cy2 + kCand; double* csc = car + kCand;
  const double img_f = (double)imgsz[0];
  const double stride = floor(img_f / (double)kW + 0.5);
  for (int r = t; r < kCand; r += 1024) {
    if (r < kPre) {
      unsigned id = id32[r];
      unsigned slot = id & 8191u;
      unsigned aidx = id >> 13;
      int a = (int)(aidx % 9u);
      int pix = (int)(aidx / 9u);
      int hh = pix / kW, ww = pix % kW;
      double sx = (double)ww * stride, sy = (double)hh * stride;
      double hwd = (double)c_hw[a], hhd = (double)c_hh[a];
      double a0 = sx - hwd, a1 = sy - hhd, a2 = sx + hwd, a3 = sy + hhd;
      double wa = a2 - a0, ha = a3 - a1;
      double cxa = a0 + 0.5 * wa, cya = a1 + 0.5 * ha;
      const double* d = rdd + ((size_t)img * kScr + slot) * 4;
      double dx = d[0], dy = d[1];
      double dw = fmin(d[2], kClampD), dh = fmin(d[3], kClampD);
      double cx = dx * wa + cxa, cy = dy * ha + cya;
      double bw2 = exp(dw) * wa, bh2 = exp(dh) * ha;
      double x1 = cx - 0.5 * bw2, y1 = cy - 0.5 * bh2;
      double x2 = cx + 0.5 * bw2, y2 = cy + 0.5 * bh2;
      x1 = fmin(fmax(x1, 0.0), img_f); y1 = fmin(fmax(y1, 0.0), img_f);
      x2 = fmin(fmax(x2, 0.0), img_f); y2 = fmin(fmax(y2, 0.0), img_f);
      cx1[r] = x1; cy1[r] = y1; cx2[r] = x2; cy2[r] = y2;
      car[r] = (x2 - x1) * (y2 - y1);
      csc[r] = rsc[(size_t)img * kScr + slot];
    } else {
      cx1[r] = 0.0; cy1[r] = 0.0; cx2[r] = 0.0; cy2[r] = 0.0;
      car[r] = 0.0; csc[r] = -1e9;
    }
  }
}

// ============ NMS suppression bitmask (row-major, upper triangle) ==========
__global__ __launch_bounds__(64) void mask_kernel(
    const double* __restrict__ cand, uint64_t* __restrict__ mask)
{
  const int img = blockIdx.z, bi = blockIdx.y, b8 = blockIdx.x;
  if (bi >= (b8 + 1) * 8) return;
  const int i = bi * 64 + (int)threadIdx.x;
  const double* cx1 = cand + (size_t)img * 6 * kCand;
  const double* cy1 = cx1 + kCand; const double* cx2 = cy1 + kCand;
  const double* cy2 = cx2 + kCand; const double* car = cy2 + kCand;
  __shared__ double jb[5][512];
  const int j0base = b8 * 512;
  for (int e = (int)threadIdx.x; e < 512; e += 64) {
    int j = j0base + e;
    jb[0][e] = cx1[j]; jb[1][e] = cy1[j]; jb[2][e] = cx2[j];
    jb[3][e] = cy2[j]; jb[4][e] = car[j];
  }
  __syncthreads();
  const double x1 = cx1[i], y1 = cy1[i], x2 = cx2[i], y2 = cy2[i], ar = car[i];
  uint64_t row[8];
  #pragma unroll
  for (int wi = 0; wi < 8; ++wi) {
    const int w = b8 * 8 + wi;
    uint64_t bits = 0;
    if (w < kWords) {
      const int e0 = wi * 64;
      for (int jj = 0; jj < 64; ++jj) {
        const int e = e0 + jj;
        double ix1 = fmax(x1, jb[0][e]);
        double iy1 = fmax(y1, jb[1][e]);
        double ix2 = fmin(x2, jb[2][e]);
        double iy2 = fmin(y2, jb[3][e]);
        double inter = fmax(ix2 - ix1, 0.0) * fmax(iy2 - iy1, 0.0);
        double denom = fmax(ar + jb[4][e] - inter, 1e-9);
        bits |= (uint64_t)(inter > 0.7 * denom) << jj;
      }
    }
    row[wi] = bits;
  }
  uint64_t* rp = mask + ((size_t)img * kCand + i) * kRowW + b8 * 8;
  #pragma unroll
  for (int wi = 0; wi < 8; ++wi)
    if (b8 * 8 + wi < kWords) rp[wi] = row[wi];
}

// ===== serial greedy scan, depth-3 speculative row prefetch + output ======
__global__ __launch_bounds__(64) void scan_kernel(
    const double* __restrict__ cand, const uint64_t* __restrict__ mask,
    float* __restrict__ out)
{
  const int img = blockIdx.x;
  const int lane = (int)threadIdx.x;
  __shared__ uint64_t rem[kWords];
  __shared__ unsigned short keep[kPost];
  for (int w = lane; w < kWords; w += 64) rem[w] = 0;
  __syncthreads();
  const uint64_t* mb = mask + (size_t)img * kCand * kRowW;

  auto loadrow = [&](int row, uint64_t& lo, uint64_t& hi) {
    const uint64_t* r = mb + (size_t)row * kRowW;
    lo = r[lane];
    hi = (lane + 64 < kWords) ? r[lane + 64] : 0ull;
  };
  auto next_clear = [&](int j) -> int {
    int w0 = j >> 6;
    uint64_t v = ~rem[lane];
    if (lane < w0) v = 0;
    else if (lane == w0) v &= ~((2ull << (j & 63)) - 1ull);
    if (lane == kWords - 1) v &= (1ull << 48) - 1ull;
    uint64_t ball = __ballot(v != 0ull);
    if (ball) {
      int L = __ffsll((unsigned long long)ball) - 1;
      uint64_t vv = __shfl(v, L);
      return L * 64 + __ffsll((unsigned long long)vv) - 1;
    }
    int w2 = lane + 64;
    uint64_t v2 = (w2 < kWords) ? ~rem[w2] : 0ull;
    if (w2 < w0) v2 = 0;
    else if (w2 == w0) v2 &= ~((2ull << (j & 63)) - 1ull);
    if (w2 == kWords - 1) v2 &= (1ull << 48) - 1ull;
    uint64_t ball2 = __ballot(v2 != 0ull);
    if (ball2) {
      int L = __ffsll((unsigned long long)ball2) - 1;
      uint64_t vv = __shfl(v2, L);
      return (L + 64) * 64 + __ffsll((unsigned long long)vv) - 1;
    }
    return kPre;
  };

  int cnt = 0;
  int j0 = 0, j1 = 1, j2 = 2;
  uint64_t aLo, aHi, bLo, bHi, cLo, cHi;
  loadrow(0, aLo, aHi);
  loadrow(1, bLo, bHi);
  loadrow(2, cLo, cHi);
  while (true) {
    if (lane == 0) keep[cnt] = (unsigned short)j0;
    ++cnt;
    if (cnt >= kPost) break;
    rem[lane] |= aLo;
    if (lane + 64 < kWords) rem[lane + 64] |= aHi;
    __syncthreads();
    int jr = next_clear(j0);
    if (jr >= kPre) break;
    if (jr != j1) { j1 = jr; loadrow(j1, bLo, bHi); }
    int j2p = next_clear(j1);
    if (j2p != j2) { j2 = j2p; if (j2 < kPre) loadrow(j2, cLo, cHi); }
    int j3 = (j2 < kPre) ? next_clear(j2) : kPre;
    uint64_t dLo = 0, dHi = 0;
    if (j3 < kPre) loadrow(j3, dLo, dHi);
    aLo = bLo; aHi = bHi; bLo = cLo; bHi = cHi; cLo = dLo; cHi = dHi;
    j0 = j1; j1 = j2; j2 = j3;
    __syncthreads();
  }
  __syncthreads();
  const double* cx1 = cand + (size_t)img * 6 * kCand;
  const double* cy1 = cx1 + kCand; const double* cx2 = cy1 + kCand;
  const double* cy2 = cx2 + kCand; const double* car = cy2 + kCand;
  const double* csc = car + kCand;
  for (int r = lane; r < kPost; r += 64) {
    float b0 = 0.f, b1v = 0.f, b2 = 0.f, b3 = 0.f, s = -1e9f;
    if (r < cnt) {
      int i = keep[r];
      b0 = (float)cx1[i]; b1v = (float)cy1[i];
      b2 = (float)cx2[i]; b3 = (float)cy2[i]; s = (float)csc[i];
    }
    float* ob = out + ((size_t)img * kPost + r) * 4;
    ob[0] = b0; ob[1] = b1v; ob[2] = b2; ob[3] = b3;
    out[(size_t)kN * kPost * 4 + (size_t)img * kPost + r] = s;
  }
}

}  // namespace

extern "C" void kernel_launch(void* const* d_in, const int* in_sizes, int n_in,
                              void* d_out, int out_size, void* d_ws, size_t ws_size,
                              hipStream_t stream) {
  const float* feat = (const float*)d_in[0];
  const float* w1   = (const float*)d_in[1];
  const float* b1   = (const float*)d_in[2];
  const float* cw   = (const float*)d_in[3];
  const float* cb   = (const float*)d_in[4];
  const float* bwp  = (const float*)d_in[5];
  const float* bbp  = (const float*)d_in[6];
  const int*   imgsz = (const int*)d_in[7];
  float* out = (float*)d_out;
  char* ws = (char*)d_ws;

  size_t off = 0;
  auto take = [&](size_t sz) { size_t o = off; off += (sz + 255) & ~(size_t)255; return o; };
  size_t oWT     = take((size_t)1152 * 128 * 4);          // 590 KB
  size_t oScrF   = take((size_t)kN * kM * 4);             // 7.37 MB
  size_t oCandI  = take((size_t)kN * kScr * 4);           // 197 KB
  size_t oEq     = take((size_t)kN * 8192 * 4);           // 262 KB
  size_t oRsc    = take((size_t)kN * kScr * 8);           // 393 KB
  size_t oRdd    = take((size_t)kN * kScr * 4 * 8);       // 1.57 MB
  size_t oCand   = take((size_t)kN * 6 * kCand * 8);      // 2.31 MB
  size_t oMask   = take((size_t)kN * kCand * kRowW * 8);  // 36.9 MB
  if (ws_size < off) return;                              // ~49.7 MB total

  float*    wT      = (float*)(ws + oWT);
  float*    scoresF = (float*)(ws + oScrF);
  unsigned* candI   = (unsigned*)(ws + oCandI);
  unsigned* eqb     = (unsigned*)(ws + oEq);
  double*   rsc     = (double*)(ws + oRsc);
  double*   rdd     = (double*)(ws + oRdd);
  double*   cand    = (double*)(ws + oCand);
  uint64_t* mask    = (uint64_t*)(ws + oMask);

  hipLaunchKernelGGL(prep_kernel, dim3(576), dim3(256), 0, stream, w1, wT);
  hipLaunchKernelGGL(conv_screen_kernel, dim3(2, kH, kN), dim3(256), 0, stream,
                     feat, wT, b1, cw, cb, scoresF);
  hipLaunchKernelGGL(screen_kernel, dim3(kN), dim3(1024), 0, stream,
                     scoresF, candI, eqb);
  hipLaunchKernelGGL(refine_kernel, dim3(kScr / 4, kN), dim3(128), 0, stream,
                     feat, wT, b1, cw, cb, bwp, bbp, candI, rsc, rdd);
  hipLaunchKernelGGL(select_sort_decode_kernel, dim3(kN), dim3(1024), 0, stream,
                     rsc, rdd, candI, imgsz, cand);
  hipLaunchKernelGGL(mask_kernel, dim3(12, kWords, kN), dim3(64), 0, stream,
                     cand, mask);
  hipLaunchKernelGGL(scan_kernel, dim3(kN), dim3(64), 0, stream,
                     cand, mask, out);
}

// Round 8
// 2909.606 us; speedup vs baseline: 1.4847x; 1.2037x over previous
//
#include <hip/hip_runtime.h>
#include <stdint.h>
#include <math.h>

namespace {

constexpr int kH = 160, kW = 160, kN = 8;
constexpr int kHW = kH * kW;              // 25600
constexpr int kM = kHW * 9;               // 230400 anchors / image
constexpr int kPre = 6000;
constexpr int kPost = 1000;
constexpr int kCand = 6016;
constexpr int kScr = 6144;                // f32-screen candidates (superset margin 144)
constexpr int kWords = 94;                // ceil(6016/64)
constexpr int kRowW = 96;                 // padded words per mask row
constexpr double kClampD = 4.135166556742356;  // np.log(1000/16) in f64

// base-anchor half extents — f32 (reference casts base anchors to f32).
__constant__ float c_hw[9] = {
  22.627416997969522f, 16.0f, 11.313708498984761f,
  45.254833995939045f, 32.0f, 22.627416997969522f,
  90.509667991878090f, 64.0f, 45.254833995939045f};
__constant__ float c_hh[9] = {
  11.313708498984761f, 16.0f, 22.627416997969522f,
  22.627416997969522f, 32.0f, 45.254833995939045f,
  45.254833995939045f, 64.0f, 90.509667991878090f};

__device__ __forceinline__ uint64_t ordd(double d) {
  uint64_t u = (uint64_t)__double_as_longlong(d);
  return (u >> 63) ? ~u : (u | 0x8000000000000000ull);
}
__device__ __forceinline__ unsigned ordf(float f) {
  unsigned u = __float_as_uint(f);
  return (u & 0x80000000u) ? ~u : (u | 0x80000000u);
}
__device__ __forceinline__ float4 ld4(const float* p) {
  return *reinterpret_cast<const float4*>(p);
}

__device__ __forceinline__ void hist_add(unsigned* hist, unsigned bucket, bool active) {
  uint64_t same = __ballot(active ? 1 : 0);
  #pragma unroll
  for (int b = 0; b < 8; ++b) {
    uint64_t bb = __ballot((bucket >> b) & 1u);
    same &= ((bucket >> b) & 1u) ? bb : ~bb;
  }
  if (active) {
    int lane = (int)(threadIdx.x & 63);
    int leader = __ffsll((unsigned long long)same) - 1;
    if (lane == leader) atomicAdd(&hist[bucket], (unsigned)__popcll((unsigned long long)same));
  }
}

// ============ weight transpose prep: wT[R][oc] = w1[oc][R], R=ic*9+k =======
__global__ __launch_bounds__(256) void prep_kernel(
    const float* __restrict__ w1, float* __restrict__ wT)
{
  int i = blockIdx.x * 256 + (int)threadIdx.x;
  if (i < 1152 * 128) {
    int R = i >> 7, oc = i & 127;
    wT[i] = w1[(size_t)oc * 1152 + R];
  }
}

// ========== f32 SCREEN: conv3x3 + relu + cls head (9 outputs) =============
// grid (2 px-tiles of 80, 160 h, 8 n), 256 thr = 8 px-groups x 32 oc-groups.
// LDS 26.1KB -> ~5 blocks/CU for latency hiding.
struct SAf { float in_s[4][3][84]; float w_s[36][128]; };  // 4032 + 18432 = 22464
struct SBf { float x_s[128][42]; float w9[9][128]; };      // 21504 + 4608 = 26112
union SUf { SAf a; SBf b; };

__global__ __launch_bounds__(256) void conv_screen_kernel(
    const float* __restrict__ feat, const float* __restrict__ wT,
    const float* __restrict__ b1, const float* __restrict__ cw,
    const float* __restrict__ cb, float* __restrict__ scoresF)
{
  __shared__ __align__(16) SUf sm;
  const int bx = blockIdx.x, h = blockIdx.y, n = blockIdx.z;
  const int px0 = bx * 80;
  const int t = threadIdx.x;
  const int pg = t & 7, og = t >> 3;
  const float* fbase = feat + (size_t)n * 128 * kHW;

  float acc[4][10];
  #pragma unroll
  for (int oi = 0; oi < 4; ++oi)
    #pragma unroll
    for (int pi = 0; pi < 10; ++pi) acc[oi][pi] = 0.f;

  for (int ic0 = 0; ic0 < 128; ic0 += 4) {
    __syncthreads();
    // stage input: 4 ic x 3 rows x 82 cols (col c -> w = px0-1+c)
    for (int idx = t; idx < 984; idx += 256) {
      int c = idx % 82, q2 = idx / 82, rr = q2 % 3, ic = q2 / 3;
      int wcol = px0 - 1 + c, hh2 = h - 1 + rr;
      float v = 0.f;
      if ((unsigned)wcol < (unsigned)kW && (unsigned)hh2 < (unsigned)kH)
        v = fbase[((size_t)(ic0 + ic) * kH + hh2) * kW + wcol];
      sm.a.in_s[ic][rr][c] = v;
    }
    // stage weights: w_s[ck][oc], ck = ic_local*9 + k
    for (int idx = t; idx < 4608; idx += 256) {
      int oc = idx & 127, ck = idx >> 7;
      sm.a.w_s[ck][oc] = wT[(size_t)(ic0 * 9 + ck) * 128 + oc];
    }
    __syncthreads();
    #pragma unroll
    for (int ic = 0; ic < 4; ++ic) {
      #pragma unroll
      for (int ky = 0; ky < 3; ++ky) {
        const float* ip = &sm.a.in_s[ic][ky][pg * 10];
        float iv[12];
        #pragma unroll
        for (int q2 = 0; q2 < 6; ++q2) {
          float2 v2 = *reinterpret_cast<const float2*>(ip + 2 * q2);
          iv[2 * q2] = v2.x; iv[2 * q2 + 1] = v2.y;
        }
        #pragma unroll
        for (int kx = 0; kx < 3; ++kx) {
          float4 wv = ld4(&sm.a.w_s[ic * 9 + ky * 3 + kx][og * 4]);
          float wd[4] = {wv.x, wv.y, wv.z, wv.w};
          #pragma unroll
          for (int oi = 0; oi < 4; ++oi)
            #pragma unroll
            for (int pi = 0; pi < 10; ++pi)
              acc[oi][pi] = fmaf(wd[oi], iv[pi + kx], acc[oi][pi]);
        }
      }
    }
  }

  // head in 2 halves of 40 px
  float bias[4];
  #pragma unroll
  for (int oi = 0; oi < 4; ++oi) bias[oi] = b1[og * 4 + oi];
  for (int hf = 0; hf < 2; ++hf) {
    __syncthreads();
    if ((pg >> 2) == hf) {
      int col0 = (pg & 3) * 10;
      #pragma unroll
      for (int oi = 0; oi < 4; ++oi)
        #pragma unroll
        for (int pi = 0; pi < 10; ++pi)
          sm.b.x_s[og * 4 + oi][col0 + pi] = fmaxf(acc[oi][pi] + bias[oi], 0.f);
    }
    if (hf == 0)
      for (int idx = t; idx < 1152; idx += 256)
        sm.b.w9[idx >> 7][idx & 127] = cw[idx];
    __syncthreads();
    for (int idx = t; idx < 360; idx += 256) {
      int o = idx / 40, px = idx % 40;
      float s = 0.f;
      for (int c = 0; c < 128; ++c)
        s = fmaf(sm.b.x_s[c][px], sm.b.w9[o][c], s);
      scoresF[(size_t)n * kM + ((size_t)h * kW + px0 + hf * 40 + px) * 9 + o]
          = s + cb[o];
    }
  }
}

// ==== f32 radix top-6144 + in-LDS ascending index sort (locality) =========
__global__ __launch_bounds__(1024) void screen_kernel(
    const float* __restrict__ scoresF, unsigned* __restrict__ candIdx,
    unsigned* __restrict__ eqbuf)
{
  const int img = blockIdx.x;
  const float* sc = scoresF + (size_t)img * kM;
  __shared__ unsigned hist[256];
  __shared__ unsigned arr[8192];
  __shared__ unsigned sh_prefix, sh_pmask, sh_K, sh_cg, sh_ce, sh_ip, sh_im, sh_Ki, sh_pos;
  const int t = threadIdx.x;
  if (t == 0) { sh_prefix = 0; sh_pmask = 0; sh_K = kScr; }
  __syncthreads();
  for (int pass = 0; pass < 4; ++pass) {
    const int shift = 24 - pass * 8;
    if (t < 256) hist[t] = 0;
    __syncthreads();
    unsigned prefix = sh_prefix, pmask = sh_pmask;
    #pragma unroll 4
    for (int i = t; i < kM; i += 1024) {
      unsigned u = ordf(sc[i]);
      bool active = ((u & pmask) == prefix);
      unsigned b = (u >> shift) & 255u;
      if (pass == 0) hist_add(hist, b, active);
      else if (active) atomicAdd(&hist[b], 1u);
    }
    __syncthreads();
    if (t == 0) {
      unsigned c = 0; int b = 255;
      for (; b > 0; --b) { unsigned hh = hist[b]; if (c + hh >= sh_K) break; c += hh; }
      sh_prefix |= ((unsigned)b) << shift;
      sh_pmask  |= 0xFFu << shift;
      sh_K -= c;
    }
    __syncthreads();
  }
  const unsigned T = sh_prefix;
  const unsigned need = sh_K;
  const unsigned ngt = kScr - need;
  if (t == 0) { sh_cg = 0; sh_ce = 0; }
  __syncthreads();
  unsigned* eq = eqbuf + (size_t)img * 8192;
  #pragma unroll 4
  for (int i = t; i < kM; i += 1024) {
    unsigned u = ordf(sc[i]);
    if (u > T)      { unsigned p = atomicAdd(&sh_cg, 1u); arr[p] = (unsigned)i; }
    else if (u == T){ unsigned p = atomicAdd(&sh_ce, 1u); if (p < 8192u) eq[p] = (unsigned)i; }
  }
  __syncthreads();
  unsigned ce = sh_ce; if (ce > 8192u) ce = 8192u;
  if (ce == need) {
    for (unsigned j = t; j < need; j += 1024) arr[ngt + j] = eq[j];
  } else {
    // tie path: take `need` smallest indices among eq
    if (t == 0) { sh_ip = 0; sh_im = 0; sh_Ki = need; sh_pos = 0; }
    __syncthreads();
    for (int pass = 0; pass < 3; ++pass) {
      const int shift = 12 - pass * 6;
      if (t < 64) hist[t] = 0;
      __syncthreads();
      unsigned prefix = sh_ip, pmask = sh_im;
      for (unsigned i = t; i < ce; i += 1024) {
        unsigned v = eq[i];
        if ((v & pmask) == prefix) atomicAdd(&hist[(v >> shift) & 63u], 1u);
      }
      __syncthreads();
      if (t == 0) {
        unsigned c = 0; int b = 0;
        for (; b < 63; ++b) { unsigned hh = hist[b]; if (c + hh >= sh_Ki) break; c += hh; }
        sh_ip |= ((unsigned)b) << shift;
        sh_im |= 63u << shift;
        sh_Ki -= c;
      }
      __syncthreads();
    }
    const unsigned tau = sh_ip;
    for (unsigned i = t; i < ce; i += 1024) {
      unsigned v = eq[i];
      if (v <= tau) { unsigned p = atomicAdd(&sh_pos, 1u); arr[ngt + p] = v; }
    }
  }
  // pad + bitonic ascending sort (spatial locality for refine gather)
  for (int j = kScr + t; j < 8192; j += 1024) arr[j] = 0xFFFFFFFFu;
  __syncthreads();
  for (unsigned kk = 2; kk <= 8192; kk <<= 1) {
    for (unsigned jj = kk >> 1; jj > 0; jj >>= 1) {
      for (unsigned i = t; i < 8192; i += 1024) {
        unsigned ixj = i ^ jj;
        if (ixj > i) {
          unsigned a = arr[i], b = arr[ixj];
          bool asc = ((i & kk) == 0);
          if (asc ? (a > b) : (a < b)) { arr[i] = b; arr[ixj] = a; }
        }
      }
      __syncthreads();
    }
  }
  unsigned* tout = candIdx + (size_t)img * kScr;
  for (int r = t; r < kScr; r += 1024) tout[r] = arr[r];
}

// ==== f64 refine: 6 cands/block, 256 thr (oc x R-half), f64 LDS patches ====
__global__ __launch_bounds__(256) void refine_kernel(
    const float* __restrict__ feat, const float* __restrict__ wT,
    const float* __restrict__ b1, const float* __restrict__ cw,
    const float* __restrict__ cb, const float* __restrict__ bwp,
    const float* __restrict__ bbp, const unsigned* __restrict__ candIdx,
    double* __restrict__ rsc, double* __restrict__ rdd)
{
  const int img = blockIdx.y;
  const int s0 = blockIdx.x * 6;
  const int t = threadIdx.x;
  __shared__ double patch[6][1152];   // 55296 B
  __shared__ double xpart[128][6];    // 6144 B
  __shared__ double xa[128][6];       // 6144 B
  __shared__ double dd[6][5];
  __shared__ unsigned meta[6];
  if (t < 6) meta[t] = candIdx[(size_t)img * kScr + s0 + t];
  __syncthreads();
  const float* fb = feat + (size_t)img * 128 * kHW;
  for (int e = t; e < 6 * 384; e += 256) {
    int rr = e / 384, q = e % 384, ic = q / 3, ky = q % 3;
    unsigned idx = meta[rr];
    int pix = (int)(idx / 9u);
    int hh = pix / kW - 1 + ky, ww = pix % kW;
    float v0 = 0.f, v1 = 0.f, v2 = 0.f;
    if ((unsigned)hh < (unsigned)kH) {
      const float* row = fb + ((size_t)ic * kH + hh) * kW;
      if (ww - 1 >= 0) v0 = row[ww - 1];
      v1 = row[ww];
      if (ww + 1 < kW) v2 = row[ww + 1];
    }
    double* pp = &patch[rr][ic * 9 + ky * 3];
    pp[0] = (double)v0; pp[1] = (double)v1; pp[2] = (double)v2;
  }
  __syncthreads();
  const int oc = t & 127, half = t >> 7;
  {
    double acc[6] = {0, 0, 0, 0, 0, 0};
    const float* wp = wT + (size_t)(half * 576) * 128 + oc;
    const int Rb = half * 576;
    for (int R = 0; R < 576; R += 2) {
      double w0 = (double)wp[0], w1d = (double)wp[128];
      wp += 256;
      const int Rg = Rb + R;
      #pragma unroll
      for (int c = 0; c < 6; ++c) {
        acc[c] = fma(w0, patch[c][Rg], acc[c]);
        acc[c] = fma(w1d, patch[c][Rg + 1], acc[c]);
      }
    }
    if (half) {
      #pragma unroll
      for (int c = 0; c < 6; ++c) xpart[oc][c] = acc[c];
    }
    __syncthreads();
    if (!half) {
      double bb1 = (double)b1[oc];
      #pragma unroll
      for (int c = 0; c < 6; ++c)
        xa[oc][c] = fmax(acc[c] + xpart[oc][c] + bb1, 0.0);
    }
  }
  __syncthreads();
  if (t < 30) {
    int rr = t % 6, j = t / 6;   // j in 0..4 (4 deltas + 1 score)
    unsigned idx = meta[rr];
    int a = (int)(idx % 9u);
    const float* wr = (j < 4) ? (bwp + (size_t)(a * 4 + j) * 128)
                              : (cw + (size_t)a * 128);
    double acc = 0.0;
    for (int c = 0; c < 128; ++c) acc = fma((double)wr[c], xa[c][rr], acc);
    dd[rr][j] = acc + (double)((j < 4) ? bbp[a * 4 + j] : cb[a]);
  }
  __syncthreads();
  if (t < 6) {
    size_t s = (size_t)img * kScr + s0 + t;
    rsc[s] = dd[t][4];
    double* rd = rdd + s * 4;
    rd[0] = dd[t][0]; rd[1] = dd[t][1]; rd[2] = dd[t][2]; rd[3] = dd[t][3];
  }
}

// == exact top-6000 select + sort (f64 desc, anchor-idx asc) + decode ======
__global__ __launch_bounds__(1024) void select_sort_decode_kernel(
    const double* __restrict__ rsc, const double* __restrict__ rdd,
    const unsigned* __restrict__ candIdx, const int* __restrict__ imgsz,
    double* __restrict__ cand)
{
  const int img = blockIdx.x;
  const int t = threadIdx.x;
  __shared__ uint64_t k64[8192];
  __shared__ unsigned id32[8192];   // (anchorIdx<<13) | slot
  for (int j = t; j < 8192; j += 1024) {
    if (j < kScr) {
      k64[j] = ordd(rsc[(size_t)img * kScr + j]);
      id32[j] = (candIdx[(size_t)img * kScr + j] << 13) | (unsigned)j;
    } else { k64[j] = 0; id32[j] = 0xFFFFFFFFu; }
  }
  __syncthreads();
  for (unsigned kk = 2; kk <= 8192; kk <<= 1) {
    for (unsigned jj = kk >> 1; jj > 0; jj >>= 1) {
      for (unsigned i = t; i < 8192; i += 1024) {
        unsigned ixj = i ^ jj;
        if (ixj > i) {
          uint64_t ka = k64[i], kb = k64[ixj];
          unsigned ia = id32[i], ib = id32[ixj];
          bool desc = ((i & kk) == 0);
          bool amis = (ka < kb) || (ka == kb && ia > ib);
          if (desc ? amis : !amis) {
            k64[i] = kb; k64[ixj] = ka;
            id32[i] = ib; id32[ixj] = ia;
          }
        }
      }
      __syncthreads();
    }
  }
  double* cx1 = cand + (size_t)img * 6 * kCand;
  double* cy1 = cx1 + kCand; double* cx2 = cy1 + kCand; double* cy2 = cx2 + kCand;
  double* car = cy2 + kCand; double* csc = car + kCand;
  const double img_f = (double)imgsz[0];
  const double stride = floor(img_f / (double)kW + 0.5);
  for (int r = t; r < kCand; r += 1024) {
    if (r < kPre) {
      unsigned id = id32[r];
      unsigned slot = id & 8191u;
      unsigned aidx = id >> 13;
      int a = (int)(aidx % 9u);
      int pix = (int)(aidx / 9u);
      int hh = pix / kW, ww = pix % kW;
      double sx = (double)ww * stride, sy = (double)hh * stride;
      double hwd = (double)c_hw[a], hhd = (double)c_hh[a];
      double a0 = sx - hwd, a1 = sy - hhd, a2 = sx + hwd, a3 = sy + hhd;
      double wa = a2 - a0, ha = a3 - a1;
      double cxa = a0 + 0.5 * wa, cya = a1 + 0.5 * ha;
      const double* d = rdd + ((size_t)img * kScr + slot) * 4;
      double dx = d[0], dy = d[1];
      double dw = fmin(d[2], kClampD), dh = fmin(d[3], kClampD);
      double cx = dx * wa + cxa, cy = dy * ha + cya;
      double bw2 = exp(dw) * wa, bh2 = exp(dh) * ha;
      double x1 = cx - 0.5 * bw2, y1 = cy - 0.5 * bh2;
      double x2 = cx + 0.5 * bw2, y2 = cy + 0.5 * bh2;
      x1 = fmin(fmax(x1, 0.0), img_f); y1 = fmin(fmax(y1, 0.0), img_f);
      x2 = fmin(fmax(x2, 0.0), img_f); y2 = fmin(fmax(y2, 0.0), img_f);
      cx1[r] = x1; cy1[r] = y1; cx2[r] = x2; cy2[r] = y2;
      car[r] = (x2 - x1) * (y2 - y1);
      csc[r] = rsc[(size_t)img * kScr + slot];
    } else {
      cx1[r] = 0.0; cy1[r] = 0.0; cx2[r] = 0.0; cy2[r] = 0.0;
      car[r] = 0.0; csc[r] = -1e9;
    }
  }
}

// ==== NMS mask: f32 fast path + rigorous f64 fallback (|lhs| < 32) ========
// Error bound: coords<=1280 cast err 7.7e-5, areas<=1.64e6 cast err 0.1;
// |err(inter - 0.7*denom)| <= ~1.8 absolute -> tau=32 gives 18x margin.
__global__ __launch_bounds__(64) void mask_kernel(
    const double* __restrict__ cand, uint64_t* __restrict__ mask)
{
  const int img = blockIdx.z, bi = blockIdx.y, b8 = blockIdx.x;
  if (bi >= (b8 + 1) * 8) return;   // whole octet below diagonal: never consulted
  const int i = bi * 64 + (int)threadIdx.x;
  const double* cx1 = cand + (size_t)img * 6 * kCand;
  const double* cy1 = cx1 + kCand; const double* cx2 = cy1 + kCand;
  const double* cy2 = cx2 + kCand; const double* car = cy2 + kCand;
  __shared__ float jb[5][512];
  const int j0base = b8 * 512;
  for (int e = (int)threadIdx.x; e < 512; e += 64) {
    int j = j0base + e; if (j >= kCand) j = kCand - 1;
    jb[0][e] = (float)cx1[j]; jb[1][e] = (float)cy1[j];
    jb[2][e] = (float)cx2[j]; jb[3][e] = (float)cy2[j];
    jb[4][e] = (float)car[j];
  }
  const double x1d = cx1[i], y1d = cy1[i], x2d = cx2[i], y2d = cy2[i], ard = car[i];
  const float fx1 = (float)x1d, fy1 = (float)y1d, fx2 = (float)x2d,
              fy2 = (float)y2d, far2 = (float)ard;
  __syncthreads();
  uint64_t row[8];
  #pragma unroll
  for (int wi = 0; wi < 8; ++wi) {
    const int w = b8 * 8 + wi;
    uint64_t bits = 0;
    if (w < kWords) {
      const int e0 = wi * 64;
      uint64_t amb = 0;
      for (int jj = 0; jj < 64; ++jj) {
        const int e = e0 + jj;
        float ix1 = fmaxf(fx1, jb[0][e]);
        float iy1 = fmaxf(fy1, jb[1][e]);
        float ix2 = fminf(fx2, jb[2][e]);
        float iy2 = fminf(fy2, jb[3][e]);
        float inter = fmaxf(ix2 - ix1, 0.f) * fmaxf(iy2 - iy1, 0.f);
        float den = fmaxf(far2 + jb[4][e] - inter, 1e-9f);
        float lhs = fmaf(-0.7f, den, inter);
        bits |= (uint64_t)(lhs > 0.f) << jj;
        amb  |= (uint64_t)(fabsf(lhs) < 32.f) << jj;
      }
      while (amb) {   // exact f64 re-decision (rare)
        int jj = __ffsll((unsigned long long)amb) - 1;
        amb &= amb - 1;
        int j = j0base + wi * 64 + jj;   // j < 6016 (w < kWords)
        double ix1 = fmax(x1d, cx1[j]);
        double iy1 = fmax(y1d, cy1[j]);
        double ix2 = fmin(x2d, cx2[j]);
        double iy2 = fmin(y2d, cy2[j]);
        double inter = fmax(ix2 - ix1, 0.0) * fmax(iy2 - iy1, 0.0);
        double den = fmax(ard + car[j] - inter, 1e-9);
        uint64_t bit = (uint64_t)(inter > 0.7 * den);
        bits = (bits & ~(1ull << jj)) | (bit << jj);
      }
    }
    row[wi] = bits;
  }
  uint64_t* rp = mask + ((size_t)img * kCand + i) * kRowW + b8 * 8;
  #pragma unroll
  for (int wi = 0; wi < 8; ++wi)
    if (b8 * 8 + wi < kWords) rp[wi] = row[wi];
}

// ===== serial greedy scan: single wave, register-resident bitset ==========
__global__ __launch_bounds__(64) void scan_kernel(
    const double* __restrict__ cand, const uint64_t* __restrict__ mask,
    float* __restrict__ out)
{
  const int img = blockIdx.x;
  const int lane = (int)threadIdx.x;
  __shared__ unsigned short keep[kPost];
  const uint64_t* mb = mask + (size_t)img * kCand * kRowW;
  const bool hiValid = (lane + 64 < kWords);
  uint64_t remLo = 0, remHi = 0;

  auto loadrow = [&](int rrow, uint64_t& lo, uint64_t& hi) {
    const uint64_t* r = mb + (size_t)rrow * kRowW;
    lo = r[lane];
    hi = hiValid ? r[lane + 64] : 0ull;
  };
  auto next_clear = [&](int j) -> int {
    int w0 = j >> 6;
    uint64_t v = ~remLo;
    if (lane < w0) v = 0;
    else if (lane == w0) v &= ~((2ull << (j & 63)) - 1ull);
    if (lane == kWords - 1) v &= (1ull << 48) - 1ull;   // kPre = 93*64+48
    uint64_t ball = __ballot(v != 0ull);
    if (ball) {
      int L = __ffsll((unsigned long long)ball) - 1;
      uint64_t vv = __shfl(v, L);
      return L * 64 + __ffsll((unsigned long long)vv) - 1;
    }
    int w2 = lane + 64;
    uint64_t v2 = hiValid ? ~remHi : 0ull;
    if (w2 < w0) v2 = 0;
    else if (w2 == w0) v2 &= ~((2ull << (j & 63)) - 1ull);
    if (w2 == kWords - 1) v2 &= (1ull << 48) - 1ull;
    uint64_t ball2 = __ballot(v2 != 0ull);
    if (ball2) {
      int L = __ffsll((unsigned long long)ball2) - 1;
      uint64_t vv = __shfl(v2, L);
      return (L + 64) * 64 + __ffsll((unsigned long long)vv) - 1;
    }
    return kPre;
  };

  int cnt = 0;
  int j0 = 0, j1 = 1, j2 = 2;
  uint64_t aLo, aHi, bLo, bHi, cLo, cHi;
  loadrow(0, aLo, aHi);
  loadrow(1, bLo, bHi);
  loadrow(2, cLo, cHi);
  while (true) {
    if (lane == 0) keep[cnt] = (unsigned short)j0;
    ++cnt;
    if (cnt >= kPost) break;
    remLo |= aLo;
    if (hiValid) remHi |= aHi;
    int jr = next_clear(j0);          // authoritative next keep
    if (jr >= kPre) break;
    if (jr != j1) { j1 = jr; loadrow(j1, bLo, bHi); }
    int j2p = next_clear(j1);         // prediction (missing row j1's bits)
    if (j2p != j2) { j2 = j2p; if (j2 < kPre) loadrow(j2, cLo, cHi); }
    int j3 = (j2 < kPre) ? next_clear(j2) : kPre;
    uint64_t dLo = 0, dHi = 0;
    if (j3 < kPre) loadrow(j3, dLo, dHi);
    aLo = bLo; aHi = bHi; bLo = cLo; bHi = cHi; cLo = dLo; cHi = dHi;
    j0 = j1; j1 = j2; j2 = j3;
  }
  __syncthreads();
  const double* cx1 = cand + (size_t)img * 6 * kCand;
  const double* cy1 = cx1 + kCand; const double* cx2 = cy1 + kCand;
  const double* cy2 = cx2 + kCand; const double* car = cy2 + kCand;
  const double* csc = car + kCand;
  for (int r = lane; r < kPost; r += 64) {
    float b0 = 0.f, b1v = 0.f, b2 = 0.f, b3 = 0.f, s = -1e9f;
    if (r < cnt) {
      int i = keep[r];
      b0 = (float)cx1[i]; b1v = (float)cy1[i];
      b2 = (float)cx2[i]; b3 = (float)cy2[i]; s = (float)csc[i];
    }
    float* ob = out + ((size_t)img * kPost + r) * 4;
    ob[0] = b0; ob[1] = b1v; ob[2] = b2; ob[3] = b3;
    out[(size_t)kN * kPost * 4 + (size_t)img * kPost + r] = s;
  }
}

}  // namespace

extern "C" void kernel_launch(void* const* d_in, const int* in_sizes, int n_in,
                              void* d_out, int out_size, void* d_ws, size_t ws_size,
                              hipStream_t stream) {
  const float* feat = (const float*)d_in[0];
  const float* w1   = (const float*)d_in[1];
  const float* b1   = (const float*)d_in[2];
  const float* cw   = (const float*)d_in[3];
  const float* cb   = (const float*)d_in[4];
  const float* bwp  = (const float*)d_in[5];
  const float* bbp  = (const float*)d_in[6];
  const int*   imgsz = (const int*)d_in[7];
  float* out = (float*)d_out;
  char* ws = (char*)d_ws;

  size_t off = 0;
  auto take = [&](size_t sz) { size_t o = off; off += (sz + 255) & ~(size_t)255; return o; };
  size_t oWT     = take((size_t)1152 * 128 * 4);
  size_t oScrF   = take((size_t)kN * kM * 4);
  size_t oCandI  = take((size_t)kN * kScr * 4);
  size_t oEq     = take((size_t)kN * 8192 * 4);
  size_t oRsc    = take((size_t)kN * kScr * 8);
  size_t oRdd    = take((size_t)kN * kScr * 4 * 8);
  size_t oCand   = take((size_t)kN * 6 * kCand * 8);
  size_t oMask   = take((size_t)kN * kCand * kRowW * 8);
  if (ws_size < off) return;

  float*    wT      = (float*)(ws + oWT);
  float*    scoresF = (float*)(ws + oScrF);
  unsigned* candI   = (unsigned*)(ws + oCandI);
  unsigned* eqb     = (unsigned*)(ws + oEq);
  double*   rsc     = (double*)(ws + oRsc);
  double*   rdd     = (double*)(ws + oRdd);
  double*   cand    = (double*)(ws + oCand);
  uint64_t* mask    = (uint64_t*)(ws + oMask);

  hipLaunchKernelGGL(prep_kernel, dim3(576), dim3(256), 0, stream, w1, wT);
  hipLaunchKernelGGL(conv_screen_kernel, dim3(2, kH, kN), dim3(256), 0, stream,
                     feat, wT, b1, cw, cb, scoresF);
  hipLaunchKernelGGL(screen_kernel, dim3(kN), dim3(1024), 0, stream,
                     scoresF, candI, eqb);
  hipLaunchKernelGGL(refine_kernel, dim3(kScr / 6, kN), dim3(256), 0, stream,
                     feat, wT, b1, cw, cb, bwp, bbp, candI, rsc, rdd);
  hipLaunchKernelGGL(select_sort_decode_kernel, dim3(kN), dim3(1024), 0, stream,
                     rsc, rdd, candI, imgsz, cand);
  hipLaunchKernelGGL(mask_kernel, dim3(12, kWords, kN), dim3(64), 0, stream,
                     cand, mask);
  hipLaunchKernelGGL(scan_kernel, dim3(kN), dim3(64), 0, stream,
                     cand, mask, out);
}

// Round 9
// 2664.747 us; speedup vs baseline: 1.6211x; 1.0919x over previous
//
#include <hip/hip_runtime.h>
#include <stdint.h>
#include <math.h>

namespace {

constexpr int kH = 160, kW = 160, kN = 8;
constexpr int kHW = kH * kW;              // 25600
constexpr int kM = kHW * 9;               // 230400 anchors / image
constexpr int kPre = 6000;
constexpr int kPost = 1000;
constexpr int kCand = 6016;
constexpr int kScr = 8192;                // bf16-screen candidates (margin 2192 ranks ~ 19 sigma)
constexpr int kWords = 94;                // ceil(6016/64)
constexpr int kRowW = 96;                 // padded words per mask row
constexpr double kClampD = 4.135166556742356;  // np.log(1000/16) in f64

typedef short short8 __attribute__((ext_vector_type(8)));
typedef float f32x4 __attribute__((ext_vector_type(4)));

// base-anchor half extents — f32 (reference casts base anchors to f32).
__constant__ float c_hw[9] = {
  22.627416997969522f, 16.0f, 11.313708498984761f,
  45.254833995939045f, 32.0f, 22.627416997969522f,
  90.509667991878090f, 64.0f, 45.254833995939045f};
__constant__ float c_hh[9] = {
  11.313708498984761f, 16.0f, 22.627416997969522f,
  22.627416997969522f, 32.0f, 45.254833995939045f,
  45.254833995939045f, 64.0f, 90.509667991878090f};

__device__ __forceinline__ uint64_t ordd(double d) {
  uint64_t u = (uint64_t)__double_as_longlong(d);
  return (u >> 63) ? ~u : (u | 0x8000000000000000ull);
}
__device__ __forceinline__ unsigned ordf(float f) {
  unsigned u = __float_as_uint(f);
  return (u & 0x80000000u) ? ~u : (u | 0x80000000u);
}
__device__ __forceinline__ float4 ld4(const float* p) {
  return *reinterpret_cast<const float4*>(p);
}
__device__ __forceinline__ unsigned short f2bf(float f) {
  unsigned u = __float_as_uint(f);
  unsigned r = (u + 0x7FFFu + ((u >> 16) & 1u)) >> 16;   // RNE
  return (unsigned short)r;
}

__device__ __forceinline__ void hist_add(unsigned* hist, unsigned bucket, bool active) {
  uint64_t same = __ballot(active ? 1 : 0);
  #pragma unroll
  for (int b = 0; b < 8; ++b) {
    uint64_t bb = __ballot((bucket >> b) & 1u);
    same &= ((bucket >> b) & 1u) ? bb : ~bb;
  }
  if (active) {
    int lane = (int)(threadIdx.x & 63);
    int leader = __ffsll((unsigned long long)same) - 1;
    if (lane == leader) atomicAdd(&hist[bucket], (unsigned)__popcll((unsigned long long)same));
  }
}

// ============ weight preps =================================================
// wT[R][oc] = w1[oc][R], R = ic*9 + k (f32, for refine)
__global__ __launch_bounds__(256) void prep_kernel(
    const float* __restrict__ w1, float* __restrict__ wT)
{
  int i = blockIdx.x * 256 + (int)threadIdx.x;
  if (i < 1152 * 128) {
    int R = i >> 7, oc = i & 127;
    wT[i] = w1[(size_t)oc * 1152 + R];
  }
}
// wBf[k9][oc][ic] = bf16(w1[oc][ic][k9]) — ic contiguous (MFMA B operand)
__global__ __launch_bounds__(256) void prep_bf_kernel(
    const float* __restrict__ w1, short* __restrict__ wBf)
{
  int i = blockIdx.x * 256 + (int)threadIdx.x;
  if (i < 9 * 128 * 128) {
    int ic = i & 127, q = i >> 7;
    int oc = q & 127, k9 = q >> 7;
    wBf[i] = (short)f2bf(w1[(size_t)oc * 1152 + ic * 9 + k9]);
  }
}

// ========== bf16 MFMA SCREEN: conv3x3 + relu + cls head ====================
// Block = one row h (M=160 px) x 128 oc; 256 thr = 4 waves x 32 oc each.
// A staged in LDS bf16 [3 ky][162 px][32 ic], XOR chunk swizzle (<=2-way).
// mfma_f32_16x16x32_bf16: A lane: row=l%16, k=8*(l/16)+j; B: k=8*(l/16)+j,
// col=l%16; C/D: col=l&15, row=(l>>4)*4+reg [guide §3, m89].
struct SConv {
  union {
    unsigned short A[3 * 162 * 32];   // 31104 B (MFMA phase)
    unsigned short X[160 * 136];      // 43520 B (head phase)
  } u;
  float w9[9][128];                   // 4608 B
};

__global__ __launch_bounds__(256) void conv_mfma_kernel(
    const float* __restrict__ feat, const short* __restrict__ wBf,
    const float* __restrict__ b1f, const float* __restrict__ cw,
    const float* __restrict__ cb, float* __restrict__ scoresF)
{
  __shared__ SConv sm;
  const int h = blockIdx.x, n = blockIdx.y;
  const int t = threadIdx.x;
  const int lane = t & 63, wave = t >> 6;
  const int l15 = lane & 15, l4 = lane >> 4;
  const float* fbase = feat + (size_t)n * 128 * kHW;

  f32x4 acc[10][2];
  #pragma unroll
  for (int mf = 0; mf < 10; ++mf)
    #pragma unroll
    for (int nf = 0; nf < 2; ++nf)
      #pragma unroll
      for (int r = 0; r < 4; ++r) acc[mf][nf][r] = 0.f;

  for (int i = t; i < 1152; i += 256) sm.w9[i >> 7][i & 127] = cw[i];

  for (int ib = 0; ib < 4; ++ib) {
    __syncthreads();
    // stage A: 12 (R,icb) tasks over 4 waves; lanes cover px
    #pragma unroll
    for (int pair = 0; pair < 3; ++pair) {
      int p = wave + 4 * pair;          // 0..11
      int R = p >> 2, icb = p & 3;
      int hh = h - 1 + R;
      bool rowok = (unsigned)hh < (unsigned)kH;
      for (int pxi = 0; pxi < 3; ++pxi) {
        int px = lane + 64 * pxi;
        if (px >= 162) break;
        int w = px - 1;
        bool ok = rowok && (unsigned)w < (unsigned)kW;
        const float* gp = fbase + ((size_t)(ib * 32 + icb * 8) * kH + hh) * kW + w;
        short8 v;
        #pragma unroll
        for (int j = 0; j < 8; ++j) {
          float f = ok ? gp[(size_t)j * kHW] : 0.f;
          v[j] = (short)f2bf(f);
        }
        int row = R * 162 + px;
        int chunk = icb ^ (row & 3) ^ ((row >> 2) & 3);
        *(short8*)&sm.u.A[(row * 4 + chunk) * 8] = v;
      }
    }
    __syncthreads();
    const int myoc0 = wave * 32;
    for (int k9 = 0; k9 < 9; ++k9) {
      int ky = k9 / 3, kx = k9 - 3 * ky;
      const short* wb = wBf + ((size_t)k9 * 128 + myoc0 + l15) * 128 + ib * 32 + 8 * l4;
      short8 bf0 = *(const short8*)wb;
      short8 bf1 = *(const short8*)(wb + 16 * 128);
      #pragma unroll
      for (int mf = 0; mf < 10; ++mf) {
        int row = ky * 162 + mf * 16 + l15 + kx;
        int chunk = l4 ^ (row & 3) ^ ((row >> 2) & 3);
        short8 af = *(const short8*)&sm.u.A[(row * 4 + chunk) * 8];
        acc[mf][0] = __builtin_amdgcn_mfma_f32_16x16x32_bf16(af, bf0, acc[mf][0], 0, 0, 0);
        acc[mf][1] = __builtin_amdgcn_mfma_f32_16x16x32_bf16(af, bf1, acc[mf][1], 0, 0, 0);
      }
    }
  }
  __syncthreads();
  // X = relu(conv + b1) -> LDS bf16 [160][136]
  float b1v[2] = { b1f[wave * 32 + l15], b1f[wave * 32 + 16 + l15] };
  #pragma unroll
  for (int mf = 0; mf < 10; ++mf)
    #pragma unroll
    for (int nf = 0; nf < 2; ++nf) {
      int oc = wave * 32 + nf * 16 + l15;
      #pragma unroll
      for (int reg = 0; reg < 4; ++reg) {
        int px = mf * 16 + l4 * 4 + reg;
        float v = fmaxf(acc[mf][nf][reg] + b1v[nf], 0.f);
        sm.u.X[px * 136 + oc] = f2bf(v);
      }
    }
  __syncthreads();
  // cls head: 9 x 160 dots over 128 (f32 accum, bf16 x)
  for (int idx = t; idx < 1440; idx += 256) {
    int o = idx / 160, px = idx - 160 * o;
    const float* wr = sm.w9[o];
    float s = 0.f;
    #pragma unroll 4
    for (int c8 = 0; c8 < 16; ++c8) {
      short8 xv = *(const short8*)&sm.u.X[px * 136 + c8 * 8];
      #pragma unroll
      for (int j = 0; j < 8; ++j) {
        float xf = __uint_as_float(((unsigned)(unsigned short)xv[j]) << 16);
        s = fmaf(xf, wr[c8 * 8 + j], s);
      }
    }
    scoresF[(size_t)n * kM + ((size_t)h * kW + px) * 9 + o] = s + cb[o];
  }
}

// ==== f32 radix top-8192 + in-LDS ascending index sort (locality) =========
__global__ __launch_bounds__(1024) void screen_kernel(
    const float* __restrict__ scoresF, unsigned* __restrict__ candIdx,
    unsigned* __restrict__ eqbuf)
{
  const int img = blockIdx.x;
  const float* sc = scoresF + (size_t)img * kM;
  __shared__ unsigned hist[256];
  __shared__ unsigned arr[8192];
  __shared__ unsigned sh_prefix, sh_pmask, sh_K, sh_cg, sh_ce, sh_ip, sh_im, sh_Ki, sh_pos;
  const int t = threadIdx.x;
  if (t == 0) { sh_prefix = 0; sh_pmask = 0; sh_K = kScr; }
  __syncthreads();
  for (int pass = 0; pass < 4; ++pass) {
    const int shift = 24 - pass * 8;
    if (t < 256) hist[t] = 0;
    __syncthreads();
    unsigned prefix = sh_prefix, pmask = sh_pmask;
    #pragma unroll 4
    for (int i = t; i < kM; i += 1024) {
      unsigned u = ordf(sc[i]);
      bool active = ((u & pmask) == prefix);
      unsigned b = (u >> shift) & 255u;
      if (pass == 0) hist_add(hist, b, active);
      else if (active) atomicAdd(&hist[b], 1u);
    }
    __syncthreads();
    if (t == 0) {
      unsigned c = 0; int b = 255;
      for (; b > 0; --b) { unsigned hh = hist[b]; if (c + hh >= sh_K) break; c += hh; }
      sh_prefix |= ((unsigned)b) << shift;
      sh_pmask  |= 0xFFu << shift;
      sh_K -= c;
    }
    __syncthreads();
  }
  const unsigned T = sh_prefix;
  const unsigned need = sh_K;
  const unsigned ngt = kScr - need;
  if (t == 0) { sh_cg = 0; sh_ce = 0; }
  __syncthreads();
  unsigned* eq = eqbuf + (size_t)img * 8192;
  #pragma unroll 4
  for (int i = t; i < kM; i += 1024) {
    unsigned u = ordf(sc[i]);
    if (u > T)      { unsigned p = atomicAdd(&sh_cg, 1u); arr[p] = (unsigned)i; }
    else if (u == T){ unsigned p = atomicAdd(&sh_ce, 1u); if (p < 8192u) eq[p] = (unsigned)i; }
  }
  __syncthreads();
  unsigned ce = sh_ce; if (ce > 8192u) ce = 8192u;
  if (ce == need) {
    for (unsigned j = t; j < need; j += 1024) arr[ngt + j] = eq[j];
  } else {
    if (t == 0) { sh_ip = 0; sh_im = 0; sh_Ki = need; sh_pos = 0; }
    __syncthreads();
    for (int pass = 0; pass < 3; ++pass) {
      const int shift = 12 - pass * 6;
      if (t < 64) hist[t] = 0;
      __syncthreads();
      unsigned prefix = sh_ip, pmask = sh_im;
      for (unsigned i = t; i < ce; i += 1024) {
        unsigned v = eq[i];
        if ((v & pmask) == prefix) atomicAdd(&hist[(v >> shift) & 63u], 1u);
      }
      __syncthreads();
      if (t == 0) {
        unsigned c = 0; int b = 0;
        for (; b < 63; ++b) { unsigned hh = hist[b]; if (c + hh >= sh_Ki) break; c += hh; }
        sh_ip |= ((unsigned)b) << shift;
        sh_im |= 63u << shift;
        sh_Ki -= c;
      }
      __syncthreads();
    }
    const unsigned tau = sh_ip;
    for (unsigned i = t; i < ce; i += 1024) {
      unsigned v = eq[i];
      if (v <= tau) { unsigned p = atomicAdd(&sh_pos, 1u); arr[ngt + p] = v; }
    }
  }
  for (int j = kScr + t; j < 8192; j += 1024) arr[j] = 0xFFFFFFFFu;
  __syncthreads();
  for (unsigned kk = 2; kk <= 8192; kk <<= 1) {
    for (unsigned jj = kk >> 1; jj > 0; jj >>= 1) {
      for (unsigned i = t; i < 8192; i += 1024) {
        unsigned ixj = i ^ jj;
        if (ixj > i) {
          unsigned a = arr[i], b = arr[ixj];
          bool asc = ((i & kk) == 0);
          if (asc ? (a > b) : (a < b)) { arr[i] = b; arr[ixj] = a; }
        }
      }
      __syncthreads();
    }
  }
  unsigned* tout = candIdx + (size_t)img * kScr;
  for (int r = t; r < kScr; r += 1024) tout[r] = arr[r];
}

// ==== f64 refine: 6 cands/block, 256 thr (oc x R-half), f64 LDS patches ====
__global__ __launch_bounds__(256) void refine_kernel(
    const float* __restrict__ feat, const float* __restrict__ wT,
    const float* __restrict__ b1, const float* __restrict__ cw,
    const float* __restrict__ cb, const float* __restrict__ bwp,
    const float* __restrict__ bbp, const unsigned* __restrict__ candIdx,
    double* __restrict__ rsc, double* __restrict__ rdd)
{
  const int img = blockIdx.y;
  const int s0 = blockIdx.x * 6;
  const int t = threadIdx.x;
  __shared__ double patch[6][1152];
  __shared__ double xpart[128][6];
  __shared__ double xa[128][6];
  __shared__ double dd[6][5];
  __shared__ unsigned meta[6];
  if (t < 6) {
    int s = s0 + t;
    meta[t] = candIdx[(size_t)img * kScr + (s < kScr ? s : kScr - 1)];
  }
  __syncthreads();
  const float* fb = feat + (size_t)img * 128 * kHW;
  for (int e = t; e < 6 * 384; e += 256) {
    int rr = e / 384, q = e % 384, ic = q / 3, ky = q % 3;
    unsigned idx = meta[rr];
    int pix = (int)(idx / 9u);
    int hh = pix / kW - 1 + ky, ww = pix % kW;
    float v0 = 0.f, v1 = 0.f, v2 = 0.f;
    if ((unsigned)hh < (unsigned)kH) {
      const float* row = fb + ((size_t)ic * kH + hh) * kW;
      if (ww - 1 >= 0) v0 = row[ww - 1];
      v1 = row[ww];
      if (ww + 1 < kW) v2 = row[ww + 1];
    }
    double* pp = &patch[rr][ic * 9 + ky * 3];
    pp[0] = (double)v0; pp[1] = (double)v1; pp[2] = (double)v2;
  }
  __syncthreads();
  const int oc = t & 127, half = t >> 7;
  {
    double acc[6] = {0, 0, 0, 0, 0, 0};
    const float* wp = wT + (size_t)(half * 576) * 128 + oc;
    const int Rb = half * 576;
    for (int R = 0; R < 576; R += 2) {
      double w0 = (double)wp[0], w1d = (double)wp[128];
      wp += 256;
      const int Rg = Rb + R;
      #pragma unroll
      for (int c = 0; c < 6; ++c) {
        acc[c] = fma(w0, patch[c][Rg], acc[c]);
        acc[c] = fma(w1d, patch[c][Rg + 1], acc[c]);
      }
    }
    if (half) {
      #pragma unroll
      for (int c = 0; c < 6; ++c) xpart[oc][c] = acc[c];
    }
    __syncthreads();
    if (!half) {
      double bb1 = (double)b1[oc];
      #pragma unroll
      for (int c = 0; c < 6; ++c)
        xa[oc][c] = fmax(acc[c] + xpart[oc][c] + bb1, 0.0);
    }
  }
  __syncthreads();
  if (t < 30) {
    int rr = t % 6, j = t / 6;
    unsigned idx = meta[rr];
    int a = (int)(idx % 9u);
    const float* wr = (j < 4) ? (bwp + (size_t)(a * 4 + j) * 128)
                              : (cw + (size_t)a * 128);
    double acc = 0.0;
    for (int c = 0; c < 128; ++c) acc = fma((double)wr[c], xa[c][rr], acc);
    dd[rr][j] = acc + (double)((j < 4) ? bbp[a * 4 + j] : cb[a]);
  }
  __syncthreads();
  if (t < 6 && s0 + t < kScr) {
    size_t s = (size_t)img * kScr + s0 + t;
    rsc[s] = dd[t][4];
    double* rd = rdd + s * 4;
    rd[0] = dd[t][0]; rd[1] = dd[t][1]; rd[2] = dd[t][2]; rd[3] = dd[t][3];
  }
}

// == exact top-6000 select + sort (f64 desc, anchor-idx asc) + decode ======
__global__ __launch_bounds__(1024) void select_sort_decode_kernel(
    const double* __restrict__ rsc, const double* __restrict__ rdd,
    const unsigned* __restrict__ candIdx, const int* __restrict__ imgsz,
    double* __restrict__ cand)
{
  const int img = blockIdx.x;
  const int t = threadIdx.x;
  __shared__ uint64_t k64[8192];
  __shared__ unsigned id32[8192];   // (anchorIdx<<13) | slot
  for (int j = t; j < 8192; j += 1024) {
    if (j < kScr) {
      k64[j] = ordd(rsc[(size_t)img * kScr + j]);
      id32[j] = (candIdx[(size_t)img * kScr + j] << 13) | (unsigned)j;
    } else { k64[j] = 0; id32[j] = 0xFFFFFFFFu; }
  }
  __syncthreads();
  for (unsigned kk = 2; kk <= 8192; kk <<= 1) {
    for (unsigned jj = kk >> 1; jj > 0; jj >>= 1) {
      for (unsigned i = t; i < 8192; i += 1024) {
        unsigned ixj = i ^ jj;
        if (ixj > i) {
          uint64_t ka = k64[i], kb = k64[ixj];
          unsigned ia = id32[i], ib = id32[ixj];
          bool desc = ((i & kk) == 0);
          bool amis = (ka < kb) || (ka == kb && ia > ib);
          if (desc ? amis : !amis) {
            k64[i] = kb; k64[ixj] = ka;
            id32[i] = ib; id32[ixj] = ia;
          }
        }
      }
      __syncthreads();
    }
  }
  double* cx1 = cand + (size_t)img * 6 * kCand;
  double* cy1 = cx1 + kCand; double* cx2 = cy1 + kCand; double* cy2 = cx2 + kCand;
  double* car = cy2 + kCand; double* csc = car + kCand;
  const double img_f = (double)imgsz[0];
  const double stride = floor(img_f / (double)kW + 0.5);
  for (int r = t; r < kCand; r += 1024) {
    if (r < kPre) {
      unsigned id = id32[r];
      unsigned slot = id & 8191u;
      unsigned aidx = id >> 13;
      int a = (int)(aidx % 9u);
      int pix = (int)(aidx / 9u);
      int hh = pix / kW, ww = pix % kW;
      double sx = (double)ww * stride, sy = (double)hh * stride;
      double hwd = (double)c_hw[a], hhd = (double)c_hh[a];
      double a0 = sx - hwd, a1 = sy - hhd, a2 = sx + hwd, a3 = sy + hhd;
      double wa = a2 - a0, ha = a3 - a1;
      double cxa = a0 + 0.5 * wa, cya = a1 + 0.5 * ha;
      const double* d = rdd + ((size_t)img * kScr + slot) * 4;
      double dx = d[0], dy = d[1];
      double dw = fmin(d[2], kClampD), dh = fmin(d[3], kClampD);
      double cx = dx * wa + cxa, cy = dy * ha + cya;
      double bw2 = exp(dw) * wa, bh2 = exp(dh) * ha;
      double x1 = cx - 0.5 * bw2, y1 = cy - 0.5 * bh2;
      double x2 = cx + 0.5 * bw2, y2 = cy + 0.5 * bh2;
      x1 = fmin(fmax(x1, 0.0), img_f); y1 = fmin(fmax(y1, 0.0), img_f);
      x2 = fmin(fmax(x2, 0.0), img_f); y2 = fmin(fmax(y2, 0.0), img_f);
      cx1[r] = x1; cy1[r] = y1; cx2[r] = x2; cy2[r] = y2;
      car[r] = (x2 - x1) * (y2 - y1);
      csc[r] = rsc[(size_t)img * kScr + slot];
    } else {
      cx1[r] = 0.0; cy1[r] = 0.0; cx2[r] = 0.0; cy2[r] = 0.0;
      car[r] = 0.0; csc[r] = -1e9;
    }
  }
}

// ==== NMS mask: f32 fast path + rigorous f64 fallback (|lhs| < 32) ========
__global__ __launch_bounds__(64) void mask_kernel(
    const double* __restrict__ cand, uint64_t* __restrict__ mask)
{
  const int img = blockIdx.z, bi = blockIdx.y, b8 = blockIdx.x;
  if (bi >= (b8 + 1) * 8) return;
  const int i = bi * 64 + (int)threadIdx.x;
  const double* cx1 = cand + (size_t)img * 6 * kCand;
  const double* cy1 = cx1 + kCand; const double* cx2 = cy1 + kCand;
  const double* cy2 = cx2 + kCand; const double* car = cy2 + kCand;
  __shared__ float jb[5][512];
  const int j0base = b8 * 512;
  for (int e = (int)threadIdx.x; e < 512; e += 64) {
    int j = j0base + e; if (j >= kCand) j = kCand - 1;
    jb[0][e] = (float)cx1[j]; jb[1][e] = (float)cy1[j];
    jb[2][e] = (float)cx2[j]; jb[3][e] = (float)cy2[j];
    jb[4][e] = (float)car[j];
  }
  const double x1d = cx1[i], y1d = cy1[i], x2d = cx2[i], y2d = cy2[i], ard = car[i];
  const float fx1 = (float)x1d, fy1 = (float)y1d, fx2 = (float)x2d,
              fy2 = (float)y2d, far2 = (float)ard;
  __syncthreads();
  uint64_t row[8];
  #pragma unroll
  for (int wi = 0; wi < 8; ++wi) {
    const int w = b8 * 8 + wi;
    uint64_t bits = 0;
    if (w < kWords) {
      const int e0 = wi * 64;
      uint64_t amb = 0;
      for (int jj = 0; jj < 64; ++jj) {
        const int e = e0 + jj;
        float ix1 = fmaxf(fx1, jb[0][e]);
        float iy1 = fmaxf(fy1, jb[1][e]);
        float ix2 = fminf(fx2, jb[2][e]);
        float iy2 = fminf(fy2, jb[3][e]);
        float inter = fmaxf(ix2 - ix1, 0.f) * fmaxf(iy2 - iy1, 0.f);
        float den = fmaxf(far2 + jb[4][e] - inter, 1e-9f);
        float lhs = fmaf(-0.7f, den, inter);
        bits |= (uint64_t)(lhs > 0.f) << jj;
        amb  |= (uint64_t)(fabsf(lhs) < 32.f) << jj;
      }
      while (amb) {
        int jj = __ffsll((unsigned long long)amb) - 1;
        amb &= amb - 1;
        int j = j0base + wi * 64 + jj;
        double ix1 = fmax(x1d, cx1[j]);
        double iy1 = fmax(y1d, cy1[j]);
        double ix2 = fmin(x2d, cx2[j]);
        double iy2 = fmin(y2d, cy2[j]);
        double inter = fmax(ix2 - ix1, 0.0) * fmax(iy2 - iy1, 0.0);
        double den = fmax(ard + car[j] - inter, 1e-9);
        uint64_t bit = (uint64_t)(inter > 0.7 * den);
        bits = (bits & ~(1ull << jj)) | (bit << jj);
      }
    }
    row[wi] = bits;
  }
  uint64_t* rp = mask + ((size_t)img * kCand + i) * kRowW + b8 * 8;
  #pragma unroll
  for (int wi = 0; wi < 8; ++wi)
    if (b8 * 8 + wi < kWords) rp[wi] = row[wi];
}

// ===== serial greedy scan: single wave, register-resident bitset ==========
__global__ __launch_bounds__(64) void scan_kernel(
    const double* __restrict__ cand, const uint64_t* __restrict__ mask,
    float* __restrict__ out)
{
  const int img = blockIdx.x;
  const int lane = (int)threadIdx.x;
  __shared__ unsigned short keep[kPost];
  const uint64_t* mb = mask + (size_t)img * kCand * kRowW;
  const bool hiValid = (lane + 64 < kWords);
  uint64_t remLo = 0, remHi = 0;

  auto loadrow = [&](int rrow, uint64_t& lo, uint64_t& hi) {
    const uint64_t* r = mb + (size_t)rrow * kRowW;
    lo = r[lane];
    hi = hiValid ? r[lane + 64] : 0ull;
  };
  auto next_clear = [&](int j) -> int {
    int w0 = j >> 6;
    uint64_t v = ~remLo;
    if (lane < w0) v = 0;
    else if (lane == w0) v &= ~((2ull << (j & 63)) - 1ull);
    if (lane == kWords - 1) v &= (1ull << 48) - 1ull;
    uint64_t ball = __ballot(v != 0ull);
    if (ball) {
      int L = __ffsll((unsigned long long)ball) - 1;
      uint64_t vv = __shfl(v, L);
      return L * 64 + __ffsll((unsigned long long)vv) - 1;
    }
    int w2 = lane + 64;
    uint64_t v2 = hiValid ? ~remHi : 0ull;
    if (w2 < w0) v2 = 0;
    else if (w2 == w0) v2 &= ~((2ull << (j & 63)) - 1ull);
    if (w2 == kWords - 1) v2 &= (1ull << 48) - 1ull;
    uint64_t ball2 = __ballot(v2 != 0ull);
    if (ball2) {
      int L = __ffsll((unsigned long long)ball2) - 1;
      uint64_t vv = __shfl(v2, L);
      return (L + 64) * 64 + __ffsll((unsigned long long)vv) - 1;
    }
    return kPre;
  };

  int cnt = 0;
  int j0 = 0, j1 = 1, j2 = 2;
  uint64_t aLo, aHi, bLo, bHi, cLo, cHi;
  loadrow(0, aLo, aHi);
  loadrow(1, bLo, bHi);
  loadrow(2, cLo, cHi);
  while (true) {
    if (lane == 0) keep[cnt] = (unsigned short)j0;
    ++cnt;
    if (cnt >= kPost) break;
    remLo |= aLo;
    if (hiValid) remHi |= aHi;
    int jr = next_clear(j0);
    if (jr >= kPre) break;
    if (jr != j1) { j1 = jr; loadrow(j1, bLo, bHi); }
    int j2p = next_clear(j1);
    if (j2p != j2) { j2 = j2p; if (j2 < kPre) loadrow(j2, cLo, cHi); }
    int j3 = (j2 < kPre) ? next_clear(j2) : kPre;
    uint64_t dLo = 0, dHi = 0;
    if (j3 < kPre) loadrow(j3, dLo, dHi);
    aLo = bLo; aHi = bHi; bLo = cLo; bHi = cHi; cLo = dLo; cHi = dHi;
    j0 = j1; j1 = j2; j2 = j3;
  }
  __syncthreads();
  const double* cx1 = cand + (size_t)img * 6 * kCand;
  const double* cy1 = cx1 + kCand; const double* cx2 = cy1 + kCand;
  const double* cy2 = cx2 + kCand; const double* car = cy2 + kCand;
  const double* csc = car + kCand;
  for (int r = lane; r < kPost; r += 64) {
    float b0 = 0.f, b1v = 0.f, b2 = 0.f, b3 = 0.f, s = -1e9f;
    if (r < cnt) {
      int i = keep[r];
      b0 = (float)cx1[i]; b1v = (float)cy1[i];
      b2 = (float)cx2[i]; b3 = (float)cy2[i]; s = (float)csc[i];
    }
    float* ob = out + ((size_t)img * kPost + r) * 4;
    ob[0] = b0; ob[1] = b1v; ob[2] = b2; ob[3] = b3;
    out[(size_t)kN * kPost * 4 + (size_t)img * kPost + r] = s;
  }
}

}  // namespace

extern "C" void kernel_launch(void* const* d_in, const int* in_sizes, int n_in,
                              void* d_out, int out_size, void* d_ws, size_t ws_size,
                              hipStream_t stream) {
  const float* feat = (const float*)d_in[0];
  const float* w1   = (const float*)d_in[1];
  const float* b1   = (const float*)d_in[2];
  const float* cw   = (const float*)d_in[3];
  const float* cb   = (const float*)d_in[4];
  const float* bwp  = (const float*)d_in[5];
  const float* bbp  = (const float*)d_in[6];
  const int*   imgsz = (const int*)d_in[7];
  float* out = (float*)d_out;
  char* ws = (char*)d_ws;

  size_t off = 0;
  auto take = [&](size_t sz) { size_t o = off; off += (sz + 255) & ~(size_t)255; return o; };
  size_t oWT     = take((size_t)1152 * 128 * 4);
  size_t oWBf    = take((size_t)9 * 128 * 128 * 2);
  size_t oScrF   = take((size_t)kN * kM * 4);
  size_t oCandI  = take((size_t)kN * kScr * 4);
  size_t oEq     = take((size_t)kN * 8192 * 4);
  size_t oRsc    = take((size_t)kN * kScr * 8);
  size_t oRdd    = take((size_t)kN * kScr * 4 * 8);
  size_t oCand   = take((size_t)kN * 6 * kCand * 8);
  size_t oMask   = take((size_t)kN * kCand * kRowW * 8);
  if (ws_size < off) return;

  float*    wT      = (float*)(ws + oWT);
  short*    wBf     = (short*)(ws + oWBf);
  float*    scoresF = (float*)(ws + oScrF);
  unsigned* candI   = (unsigned*)(ws + oCandI);
  unsigned* eqb     = (unsigned*)(ws + oEq);
  double*   rsc     = (double*)(ws + oRsc);
  double*   rdd     = (double*)(ws + oRdd);
  double*   cand    = (double*)(ws + oCand);
  uint64_t* mask    = (uint64_t*)(ws + oMask);

  hipLaunchKernelGGL(prep_kernel, dim3(576), dim3(256), 0, stream, w1, wT);
  hipLaunchKernelGGL(prep_bf_kernel, dim3(576), dim3(256), 0, stream, w1, wBf);
  hipLaunchKernelGGL(conv_mfma_kernel, dim3(kH, kN), dim3(256), 0, stream,
                     feat, wBf, b1, cw, cb, scoresF);
  hipLaunchKernelGGL(screen_kernel, dim3(kN), dim3(1024), 0, stream,
                     scoresF, candI, eqb);
  hipLaunchKernelGGL(refine_kernel, dim3((kScr + 5) / 6, kN), dim3(256), 0, stream,
                     feat, wT, b1, cw, cb, bwp, bbp, candI, rsc, rdd);
  hipLaunchKernelGGL(select_sort_decode_kernel, dim3(kN), dim3(1024), 0, stream,
                     rsc, rdd, candI, imgsz, cand);
  hipLaunchKernelGGL(mask_kernel, dim3(12, kWords, kN), dim3(64), 0, stream,
                     cand, mask);
  hipLaunchKernelGGL(scan_kernel, dim3(kN), dim3(64), 0, stream,
                     cand, mask, out);
}